// Round 14
// baseline (641.074 us; speedup 1.0000x reference)
//
#include <hip/hip_runtime.h>
#include <hip/hip_bf16.h>
#include <math.h>
#include <stddef.h>

#define NN 8192
#define FF 128
#define HH 512
#define DDIM 256
#define EE 131072
#define ET (2*EE + NN)     // 270336 edges after symmetrize + self loops
#define FEPS 1e-8f

typedef float f32x4 __attribute__((ext_vector_type(4)));
typedef __bf16 bf16x8 __attribute__((ext_vector_type(8)));
typedef unsigned short u16;

static __device__ __forceinline__ u16 f2bf(float f) {
  union { float f; unsigned u; } v; v.f = f;
  return (u16)((v.u + 0x7fffu + ((v.u >> 16) & 1u)) >> 16);
}
static __device__ __forceinline__ float bf2f(u16 h) {
  union { unsigned u; float f; } v; v.u = ((unsigned)h) << 16;
  return v.f;
}
static __device__ __forceinline__ f32x4 mfma16(bf16x8 a, bf16x8 b, f32x4 c) {
  return __builtin_amdgcn_mfma_f32_16x16x32_bf16(a, b, c, 0, 0, 0);
}
// async global->LDS, 16B per lane.
static __device__ __forceinline__ void gload16(const void* g, void* lds) {
  __builtin_amdgcn_global_load_lds(
      (const __attribute__((address_space(1))) void*)(unsigned long long)(uintptr_t)g,
      (__attribute__((address_space(3))) void*)(unsigned int)(uintptr_t)lds,
      16, 0, 0);
}

struct PLB { const u16* p[6]; int slot[6]; };

// ======================= stage 0: global mean/std normalize (fused pair) =======================
__global__ void k_reduce2(const float* __restrict__ xa, const float* __restrict__ xb,
                          int n, double* __restrict__ out) {
  const float* x = blockIdx.y ? xb : xa;
  double* o = out + 2 * blockIdx.y;
  __shared__ double s1[256], s2[256];
  double a = 0.0, b = 0.0;
  for (int i = blockIdx.x * blockDim.x + threadIdx.x; i < n; i += gridDim.x * blockDim.x) {
    double v = (double)x[i];
    a += v; b += v * v;
  }
  s1[threadIdx.x] = a; s2[threadIdx.x] = b;
  __syncthreads();
  for (int w = 128; w > 0; w >>= 1) {
    if (threadIdx.x < w) { s1[threadIdx.x] += s1[threadIdx.x + w]; s2[threadIdx.x] += s2[threadIdx.x + w]; }
    __syncthreads();
  }
  if (threadIdx.x == 0) { atomicAdd(&o[0], s1[0]); atomicAdd(&o[1], s2[0]); }
}

__global__ void k_normalize2(const float* __restrict__ xa, const float* __restrict__ xb,
                             u16* __restrict__ ya, u16* __restrict__ yb, int n,
                             const double* __restrict__ s) {
  const float* x = blockIdx.y ? xb : xa;
  u16* y = blockIdx.y ? yb : ya;
  const double* sp = s + 2 * blockIdx.y;
  double mean = sp[0] / (double)n;
  double var = (sp[1] - (double)n * mean * mean) / (double)(n - 1);  // ddof=1
  float mu = (float)mean;
  float inv = (float)(1.0 / sqrt(var));
  for (int i = blockIdx.x * blockDim.x + threadIdx.x; i < n; i += gridDim.x * blockDim.x)
    y[i] = f2bf((x[i] - mu) * inv);
}

// ======================= GAT: CSR build =======================
__global__ void k_hist(const int* __restrict__ ei, int* __restrict__ deg) {
  int t = blockIdx.x * blockDim.x + threadIdx.x;
  if (t >= ET) return;
  int dst = (t < EE) ? ei[EE + t] : ((t < 2*EE) ? ei[t - EE] : (t - 2*EE));
  atomicAdd(&deg[dst], 1);
}

__global__ void k_scan(const int* __restrict__ deg, int* __restrict__ offs, int* __restrict__ cursor) {
  __shared__ int ts[256];
  int tid = threadIdx.x;
  int loc[32];
  int s = 0;
  #pragma unroll
  for (int i = 0; i < 32; ++i) { loc[i] = s; s += deg[tid * 32 + i]; }
  ts[tid] = s;
  __syncthreads();
  for (int off = 1; off < 256; off <<= 1) {
    int v = (tid >= off) ? ts[tid - off] : 0;
    __syncthreads();
    ts[tid] += v;
    __syncthreads();
  }
  int pre = ts[tid] - s;
  #pragma unroll
  for (int i = 0; i < 32; ++i) {
    int o = pre + loc[i];
    offs[tid * 32 + i] = o;
    cursor[tid * 32 + i] = o;
  }
  if (tid == 255) offs[NN] = ts[255];
}

__global__ void k_scatter(const int* __restrict__ ei, int* __restrict__ cursor, int* __restrict__ srcs) {
  int t = blockIdx.x * blockDim.x + threadIdx.x;
  if (t >= ET) return;
  int src = (t < 2*EE) ? ei[t] : (t - 2*EE);
  int dst = (t < EE) ? ei[EE + t] : ((t < 2*EE) ? ei[t - EE] : (t - 2*EE));
  int pos = atomicAdd(&cursor[dst], 1);
  srcs[pos] = src;
}

// ======================= transpose f32 -> bf16 (optionally squared) =======================
__global__ __launch_bounds__(256) void k_tr_bf16(const float* __restrict__ src, u16* __restrict__ dst,
                                                 int R, int C, int sq) {
  __shared__ float T[32][33];
  int tx = threadIdx.x & 31, ty = threadIdx.x >> 5;
  int r0 = blockIdx.y * 32, c0 = blockIdx.x * 32;
  #pragma unroll
  for (int p = 0; p < 4; ++p)
    T[ty + 8 * p][tx] = src[(size_t)(r0 + ty + 8 * p) * C + c0 + tx];
  __syncthreads();
  #pragma unroll
  for (int p = 0; p < 4; ++p) {
    float v = T[tx][ty + 8 * p];
    if (sq) v *= v;
    dst[(size_t)(c0 + ty + 8 * p) * R + r0 + tx] = f2bf(v);
  }
}

// fused pair transpose+scale
__global__ __launch_bounds__(256) void k_tr2w(const float* __restrict__ hA, const float* __restrict__ scA,
                                              u16* __restrict__ tA, u16* __restrict__ wA,
                                              const float* __restrict__ hB, const float* __restrict__ scB,
                                              u16* __restrict__ tB, u16* __restrict__ wB) {
  __shared__ float T[32][33];
  __shared__ float W[32][33];
  const float* src = blockIdx.z ? hB : hA;
  const float* sc  = blockIdx.z ? scB : scA;
  u16* dt = blockIdx.z ? tB : tA;
  u16* dw = blockIdx.z ? wB : wA;
  int tx = threadIdx.x & 31, ty = threadIdx.x >> 5;
  int r0 = blockIdx.y * 32, c0 = blockIdx.x * 32;
  #pragma unroll
  for (int p = 0; p < 4; ++p) {
    int j = r0 + ty + 8 * p;
    float v = src[(size_t)j * DDIM + c0 + tx];
    T[ty + 8 * p][tx] = v;
    W[ty + 8 * p][tx] = v * sc[j];
  }
  __syncthreads();
  #pragma unroll
  for (int p = 0; p < 4; ++p) {
    size_t o = (size_t)(c0 + ty + 8 * p) * NN + r0 + tx;
    dt[o] = f2bf(T[tx][ty + 8 * p]);
    dw[o] = f2bf(W[tx][ty + 8 * p]);
  }
}

// ======================= wa: attention vectors pulled through the GAT weights =======================
__global__ void k_wa(const float* __restrict__ Wg1, const float* __restrict__ a1s,
                     const float* __restrict__ a1d, const float* __restrict__ Wg2,
                     const float* __restrict__ a2s, const float* __restrict__ a2d,
                     float* __restrict__ wa) {
  int t = threadIdx.x;
  if (blockIdx.x == 0) {
    if (t < 128) {
      float s = 0.f, d = 0.f;
      for (int j = 0; j < 512; ++j) { float w = Wg1[(size_t)t * 512 + j]; s += w * a1s[j]; d += w * a1d[j]; }
      wa[t] = s; wa[128 + t] = d;
    }
  } else {
    for (int k = t; k < 512; k += 256) {
      float s = 0.f, d = 0.f;
      for (int j = 0; j < 256; ++j) { float w = Wg2[(size_t)k * 256 + j]; s += w * a2s[j]; d += w * a2d[j]; }
      wa[256 + k] = s; wa[768 + k] = d;
    }
  }
}

// dots over raw features (D=128)
__global__ void k_dots1(const u16* __restrict__ fb, const float* __restrict__ wa,
                        float* __restrict__ hs, float* __restrict__ hd) {
  int wid = (blockIdx.x * blockDim.x + threadIdx.x) >> 6;
  int lane = threadIdx.x & 63;
  if (wid >= NN) return;
  unsigned v = *reinterpret_cast<const unsigned*>(fb + (size_t)wid * 128 + lane * 2);
  float f0 = bf2f((u16)(v & 0xffff)), f1 = bf2f((u16)(v >> 16));
  float2 ws = *reinterpret_cast<const float2*>(wa + lane * 2);
  float2 wd = *reinterpret_cast<const float2*>(wa + 128 + lane * 2);
  float s = f0 * ws.x + f1 * ws.y;
  float d = f0 * wd.x + f1 * wd.y;
  #pragma unroll
  for (int o = 32; o > 0; o >>= 1) { s += __shfl_xor(s, o); d += __shfl_xor(d, o); }
  if (!lane) { hs[wid] = s; hd[wid] = d; }
}

// ======================= MFMA GEMM with optional ELU + fused attention-dot epilogue ==============
__global__ __launch_bounds__(256) void k_gemm_bf(const u16* __restrict__ A, const u16* __restrict__ Bt,
                                                 u16* __restrict__ Cb, int K, int N, int elu,
                                                 const float* __restrict__ as_, const float* __restrict__ ad_,
                                                 float* __restrict__ hs, float* __restrict__ hd) {
  int w = threadIdx.x >> 6, l = threadIdx.x & 63, r15 = l & 15, g = l >> 4;
  int i0 = blockIdx.y * 64 + w * 16;
  int n0 = blockIdx.x * 128;
  f32x4 zero = {0.f, 0.f, 0.f, 0.f};
  f32x4 acc[8];
  #pragma unroll
  for (int n = 0; n < 8; ++n) acc[n] = zero;
  int kcN = K >> 5;
  const u16* arow = A + (size_t)(i0 + r15) * K + g * 8;
  for (int kc = 0; kc < kcN; ++kc) {
    bf16x8 a = *reinterpret_cast<const bf16x8*>(arow + kc * 32);
    #pragma unroll
    for (int n = 0; n < 8; ++n) {
      bf16x8 b = *reinterpret_cast<const bf16x8*>(Bt + (size_t)(n0 + n * 16 + r15) * K + kc * 32 + g * 8);
      acc[n] = mfma16(a, b, acc[n]);
    }
  }
  if (elu) {
    #pragma unroll
    for (int n = 0; n < 8; ++n)
      #pragma unroll
      for (int q = 0; q < 4; ++q)
        acc[n][q] = acc[n][q] > 0.f ? acc[n][q] : (expf(acc[n][q]) - 1.f);
  }
  int io = i0 + g * 4;
  #pragma unroll
  for (int n = 0; n < 8; ++n) {
    int c = n0 + n * 16 + r15;
    #pragma unroll
    for (int q = 0; q < 4; ++q)
      Cb[(size_t)(io + q) * N + c] = f2bf(acc[n][q]);
  }
  if (as_) {
    float hsum[4] = {0.f, 0.f, 0.f, 0.f}, dsum[4] = {0.f, 0.f, 0.f, 0.f};
    #pragma unroll
    for (int n = 0; n < 8; ++n) {
      int c = n0 + n * 16 + r15;
      float av = as_[c], dv = ad_[c];
      #pragma unroll
      for (int q = 0; q < 4; ++q) { hsum[q] += acc[n][q] * av; dsum[q] += acc[n][q] * dv; }
    }
    #pragma unroll
    for (int q = 0; q < 4; ++q) {
      #pragma unroll
      for (int o = 1; o < 16; o <<= 1) { hsum[q] += __shfl_xor(hsum[q], o); dsum[q] += __shfl_xor(dsum[q], o); }
    }
    if (r15 == 0) {
      #pragma unroll
      for (int q = 0; q < 4; ++q) {
        atomicAdd(&hs[io + q], hsum[q]);
        atomicAdd(&hd[io + q], dsum[q]);
      }
    }
  }
}

// ======================= GAT: attention (unrolled gathers) =======================
__global__ void k_alpha(const int* __restrict__ offs, const int* __restrict__ srcs,
                        const float* __restrict__ hs, const float* __restrict__ hd,
                        float* __restrict__ alpha) {
  int wid = (blockIdx.x * blockDim.x + threadIdx.x) >> 6;
  int lane = threadIdx.x & 63;
  if (wid >= NN) return;
  int b = offs[wid], e = offs[wid + 1];
  float hdn = hd[wid];
  float m = -3.4e38f;
  {
    int p = b + lane;
    for (; p + 192 < e; p += 256) {
      int s0 = srcs[p], s1 = srcs[p + 64], s2 = srcs[p + 128], s3 = srcs[p + 192];
      float v0 = hs[s0] + hdn, v1 = hs[s1] + hdn, v2 = hs[s2] + hdn, v3 = hs[s3] + hdn;
      v0 = v0 > 0.f ? v0 : 0.2f * v0; v1 = v1 > 0.f ? v1 : 0.2f * v1;
      v2 = v2 > 0.f ? v2 : 0.2f * v2; v3 = v3 > 0.f ? v3 : 0.2f * v3;
      alpha[p] = v0; alpha[p + 64] = v1; alpha[p + 128] = v2; alpha[p + 192] = v3;
      m = fmaxf(m, fmaxf(fmaxf(v0, v1), fmaxf(v2, v3)));
    }
    for (; p < e; p += 64) {
      float v = hs[srcs[p]] + hdn;
      v = v > 0.f ? v : 0.2f * v;
      alpha[p] = v;
      m = fmaxf(m, v);
    }
  }
  #pragma unroll
  for (int o = 32; o > 0; o >>= 1) m = fmaxf(m, __shfl_xor(m, o));
  float den = 0.f;
  for (int p = b + lane; p < e; p += 64) {
    float ex = expf(alpha[p] - m);
    alpha[p] = ex;
    den += ex;
  }
  #pragma unroll
  for (int o = 32; o > 0; o >>= 1) den += __shfl_xor(den, o);
  float sc = 1.f / (den + 1e-16f);
  for (int p = b + lane; p < e; p += 64) alpha[p] *= sc;
}

// aggregate raw features (D=128), wave per node, x4 unrolled gathers
__global__ __launch_bounds__(256) void k_aggf(const int* __restrict__ offs, const int* __restrict__ srcs,
                                              const float* __restrict__ alpha, const u16* __restrict__ fb,
                                              u16* __restrict__ aggout) {
  int wv = threadIdx.x >> 6, lane = threadIdx.x & 63;
  int n = blockIdx.x * 4 + wv;
  int b = offs[n], e = offs[n + 1];
  float a0 = 0.f, a1 = 0.f;
  const u16* base = fb + lane * 2;
  int p = b;
  for (; p + 4 <= e; p += 4) {
    int s0 = srcs[p], s1 = srcs[p + 1], s2 = srcs[p + 2], s3 = srcs[p + 3];
    float w0 = alpha[p], w1 = alpha[p + 1], w2 = alpha[p + 2], w3 = alpha[p + 3];
    unsigned v0 = *reinterpret_cast<const unsigned*>(base + (size_t)s0 * 128);
    unsigned v1 = *reinterpret_cast<const unsigned*>(base + (size_t)s1 * 128);
    unsigned v2 = *reinterpret_cast<const unsigned*>(base + (size_t)s2 * 128);
    unsigned v3 = *reinterpret_cast<const unsigned*>(base + (size_t)s3 * 128);
    a0 += w0 * bf2f((u16)(v0 & 0xffff)) + w1 * bf2f((u16)(v1 & 0xffff)) +
          w2 * bf2f((u16)(v2 & 0xffff)) + w3 * bf2f((u16)(v3 & 0xffff));
    a1 += w0 * bf2f((u16)(v0 >> 16)) + w1 * bf2f((u16)(v1 >> 16)) +
          w2 * bf2f((u16)(v2 >> 16)) + w3 * bf2f((u16)(v3 >> 16));
  }
  for (; p < e; ++p) {
    float a = alpha[p];
    unsigned v = *reinterpret_cast<const unsigned*>(base + (size_t)srcs[p] * 128);
    a0 += a * bf2f((u16)(v & 0xffff));
    a1 += a * bf2f((u16)(v >> 16));
  }
  unsigned o = ((unsigned)f2bf(a1) << 16) | (unsigned)f2bf(a0);
  *reinterpret_cast<unsigned*>(aggout + (size_t)n * 128 + lane * 2) = o;
}

// aggregate projected layer-2 features (D=256), wave per node, x4 unrolled gathers
__global__ __launch_bounds__(256) void k_agg3(const int* __restrict__ offs, const int* __restrict__ srcs,
                                              const float* __restrict__ alpha, const u16* __restrict__ Hb,
                                              float* __restrict__ outF, u16* __restrict__ outB) {
  int wv = threadIdx.x >> 6, lane = threadIdx.x & 63;
  int n = blockIdx.x * 4 + wv;
  int b = offs[n], e = offs[n + 1];
  float acc[4];
  #pragma unroll
  for (int j = 0; j < 4; ++j) acc[j] = 0.f;
  const u16* base = Hb + lane * 4;
  int p = b;
  for (; p + 4 <= e; p += 4) {
    int s0 = srcs[p], s1 = srcs[p + 1], s2 = srcs[p + 2], s3 = srcs[p + 3];
    float w0 = alpha[p], w1 = alpha[p + 1], w2 = alpha[p + 2], w3 = alpha[p + 3];
    uint2 v0 = *reinterpret_cast<const uint2*>(base + (size_t)s0 * 256);
    uint2 v1 = *reinterpret_cast<const uint2*>(base + (size_t)s1 * 256);
    uint2 v2 = *reinterpret_cast<const uint2*>(base + (size_t)s2 * 256);
    uint2 v3 = *reinterpret_cast<const uint2*>(base + (size_t)s3 * 256);
    acc[0] += w0 * bf2f((u16)(v0.x & 0xffff)) + w1 * bf2f((u16)(v1.x & 0xffff)) +
              w2 * bf2f((u16)(v2.x & 0xffff)) + w3 * bf2f((u16)(v3.x & 0xffff));
    acc[1] += w0 * bf2f((u16)(v0.x >> 16)) + w1 * bf2f((u16)(v1.x >> 16)) +
              w2 * bf2f((u16)(v2.x >> 16)) + w3 * bf2f((u16)(v3.x >> 16));
    acc[2] += w0 * bf2f((u16)(v0.y & 0xffff)) + w1 * bf2f((u16)(v1.y & 0xffff)) +
              w2 * bf2f((u16)(v2.y & 0xffff)) + w3 * bf2f((u16)(v3.y & 0xffff));
    acc[3] += w0 * bf2f((u16)(v0.y >> 16)) + w1 * bf2f((u16)(v1.y >> 16)) +
              w2 * bf2f((u16)(v2.y >> 16)) + w3 * bf2f((u16)(v3.y >> 16));
  }
  for (; p < e; ++p) {
    float a = alpha[p];
    uint2 v = *reinterpret_cast<const uint2*>(base + (size_t)srcs[p] * 256);
    acc[0] += a * bf2f((u16)(v.x & 0xffff)); acc[1] += a * bf2f((u16)(v.x >> 16));
    acc[2] += a * bf2f((u16)(v.y & 0xffff)); acc[3] += a * bf2f((u16)(v.y >> 16));
  }
  float4 of = {acc[0], acc[1], acc[2], acc[3]};
  *reinterpret_cast<float4*>(outF + (size_t)n * 256 + lane * 4) = of;
  ushort4 ob;
  ob.x = f2bf(acc[0]); ob.y = f2bf(acc[1]); ob.z = f2bf(acc[2]); ob.w = f2bf(acc[3]);
  *reinterpret_cast<ushort4*>(outB + (size_t)n * 256 + lane * 4) = ob;
}

// ======================= mutual: inverse row norms (fused pair) =======================
__global__ void k_rninv2(const float* __restrict__ h1, const float* __restrict__ h2,
                         float* __restrict__ o1, float* __restrict__ o2) {
  const float* h = blockIdx.y ? h2 : h1;
  float* o = blockIdx.y ? o2 : o1;
  int wid = (blockIdx.x * blockDim.x + threadIdx.x) >> 6;
  int lane = threadIdx.x & 63;
  if (wid >= NN) return;
  float4 v = *reinterpret_cast<const float4*>(h + (size_t)wid * DDIM + lane * 4);
  float a = v.x * v.x + v.y * v.y + v.z * v.z + v.w * v.w;
  #pragma unroll
  for (int o2_ = 32; o2_ > 0; o2_ >>= 1) a += __shfl_xor(a, o2_);
  if (!lane) o[wid] = 1.f / sqrtf(a);
}

// ======================= mutual rank-1 sums =======================
__global__ void k_wsum(const float* __restrict__ h1, const float* __restrict__ h2,
                       const float* __restrict__ n1inv, const float* __restrict__ n2inv,
                       float* __restrict__ ut) {
  const float* h = blockIdx.y ? h2 : h1;
  const float* wv = blockIdx.y ? n2inv : n1inv;
  float* o = ut + 256 * blockIdx.y;
  int d = threadIdx.x;
  int r0 = blockIdx.x * 128;
  float acc = 0.f;
  for (int r = 0; r < 128; ++r) acc += wv[r0 + r] * h[(size_t)(r0 + r) * 256 + d];
  atomicAdd(&o[d], acc);
}

__global__ void k_rs(const float* __restrict__ h1, const float* __restrict__ h2,
                     const float* __restrict__ n1inv, const float* __restrict__ n2inv,
                     const float* __restrict__ ut, float* __restrict__ R, float* __restrict__ S) {
  const float* h  = blockIdx.y ? h2 : h1;
  const float* ni = blockIdx.y ? n2inv : n1inv;
  const float* gv = blockIdx.y ? ut : ut + 256;
  float* o = blockIdx.y ? S : R;
  int wid = (blockIdx.x * blockDim.x + threadIdx.x) >> 6;
  int lane = threadIdx.x & 63;
  if (wid >= NN) return;
  float4 v = *reinterpret_cast<const float4*>(h + (size_t)wid * 256 + lane * 4);
  float4 g4 = *reinterpret_cast<const float4*>(gv + lane * 4);
  float a = v.x * g4.x + v.y * g4.y + v.z * g4.z + v.w * g4.w;
  #pragma unroll
  for (int o2_ = 32; o2_ > 0; o2_ >>= 1) a += __shfl_xor(a, o2_);
  if (!lane) o[wid] = ni[wid] * a;
}

__global__ void k_scj(const float* __restrict__ S, const float* __restrict__ R,
                      const float* __restrict__ n1inv, const float* __restrict__ n2inv,
                      float* __restrict__ scj1, float* __restrict__ scj2) {
  int j = blockIdx.x * blockDim.x + threadIdx.x;
  if (j >= NN) return;
  scj1[j] = n2inv[j] / S[j];
  scj2[j] = n1inv[j] / R[j];
}

// ======================= M = h^T diag(w) h  (256x256, split-K MFMA) =======================
__global__ __launch_bounds__(256) void k_gemm_M(const u16* __restrict__ A1, const u16* __restrict__ B1,
                                                const u16* __restrict__ A2, const u16* __restrict__ B2,
                                                float* __restrict__ Mf) {
  int mat = blockIdx.z & 1, kch = blockIdx.z >> 1;
  const u16* A = mat ? A2 : A1;
  const u16* Bt = mat ? B2 : B1;
  float* C = Mf + mat * 65536;
  int w = threadIdx.x >> 6, l = threadIdx.x & 63, r15 = l & 15, g = l >> 4;
  int i0 = blockIdx.y * 64 + w * 16;
  int n0 = blockIdx.x * 128;
  f32x4 zero = {0.f, 0.f, 0.f, 0.f};
  f32x4 acc[8];
  #pragma unroll
  for (int n = 0; n < 8; ++n) acc[n] = zero;
  const u16* arow = A + (size_t)(i0 + r15) * NN + g * 8;
  for (int kc = kch * 16; kc < kch * 16 + 16; ++kc) {
    bf16x8 a = *reinterpret_cast<const bf16x8*>(arow + kc * 32);
    #pragma unroll
    for (int n = 0; n < 8; ++n) {
      bf16x8 b = *reinterpret_cast<const bf16x8*>(Bt + (size_t)(n0 + n * 16 + r15) * NN + kc * 32 + g * 8);
      acc[n] = mfma16(a, b, acc[n]);
    }
  }
  int io = i0 + g * 4;
  #pragma unroll
  for (int n = 0; n < 8; ++n) {
    int c = n0 + n * 16 + r15;
    #pragma unroll
    for (int q = 0; q < 4; ++q)
      atomicAdd(&C[(size_t)(io + q) * 256 + c], acc[n][q]);
  }
}

__global__ void k_m2bf(const float* __restrict__ Mf, u16* __restrict__ Mb) {
  size_t o = (size_t)blockIdx.y * 65536 + blockIdx.x * 256 + threadIdx.x;
  Mb[o] = f2bf(Mf[o]);
}

// ======================= hXm = diag(sc) * (hXb @ M^T) -> bf16 =======================
__global__ __launch_bounds__(256) void k_gemm_hm(const u16* __restrict__ A1, const u16* __restrict__ M1,
                                                 const float* __restrict__ s1, u16* __restrict__ O1,
                                                 const u16* __restrict__ A2, const u16* __restrict__ M2,
                                                 const float* __restrict__ s2, u16* __restrict__ O2) {
  int z = blockIdx.z;
  const u16* A = z ? A2 : A1;
  const u16* Bt = z ? M2 : M1;
  const float* sc = z ? s2 : s1;
  u16* O = z ? O2 : O1;
  int w = threadIdx.x >> 6, l = threadIdx.x & 63, r15 = l & 15, g = l >> 4;
  int i0 = blockIdx.y * 64 + w * 16;
  int n0 = blockIdx.x * 128;
  f32x4 zero = {0.f, 0.f, 0.f, 0.f};
  f32x4 acc[8];
  #pragma unroll
  for (int n = 0; n < 8; ++n) acc[n] = zero;
  const u16* arow = A + (size_t)(i0 + r15) * 256 + g * 8;
  #pragma unroll
  for (int kc = 0; kc < 8; ++kc) {
    bf16x8 a = *reinterpret_cast<const bf16x8*>(arow + kc * 32);
    #pragma unroll
    for (int n = 0; n < 8; ++n) {
      bf16x8 b = *reinterpret_cast<const bf16x8*>(Bt + (size_t)(n0 + n * 16 + r15) * 256 + kc * 32 + g * 8);
      acc[n] = mfma16(a, b, acc[n]);
    }
  }
  int io = i0 + g * 4;
  float s4[4];
  #pragma unroll
  for (int q = 0; q < 4; ++q) s4[q] = sc[io + q];
  #pragma unroll
  for (int n = 0; n < 8; ++n) {
    int c = n0 + n * 16 + r15;
    #pragma unroll
    for (int q = 0; q < 4; ++q)
      O[(size_t)(io + q) * 256 + c] = f2bf(acc[n][q] * s4[q]);
  }
}

// ======================= w2d =======================
__global__ void k_w2d(const u16* __restrict__ W2t, const float* __restrict__ ogs,
                      u16* __restrict__ W2d, float* __restrict__ yn) {
  __shared__ float red[256];
  int n = blockIdx.x, z = blockIdx.y, k = threadIdx.x;
  int map = (z == 0) ? 512 : (z == 1) ? 0 : (z == 2) ? 768 : 256;
  float y = ogs[map + k];
  float wv = bf2f(W2t[n * 256 + k]);
  W2d[z * 65536 + n * 256 + k] = f2bf(wv * y);
  red[k] = wv * y * y;
  __syncthreads();
  for (int s = 128; s > 0; s >>= 1) {
    if (k < s) red[k] += red[k + s];
    __syncthreads();
  }
  if (!k) yn[z * 256 + n] = rsqrtf(fmaxf(red[0], 1e-30f));
}

// ======================= match5: fused miu/phi/psi; A LDS-staged (swizzled), Am from L2 =============
// grid (4, 128, 2), remapped so the 4 c-blocks of an (i-tile, graph) share an XCD.
// LDS 32KB -> 3 blk/CU at (256,3).
__global__ __launch_bounds__(256, 3) void k_match5(
    const u16* __restrict__ h1b, const u16* __restrict__ h1mb,
    const u16* __restrict__ h2b, const u16* __restrict__ h2mb,
    const u16* __restrict__ W2t, const u16* __restrict__ W2dB, const float* __restrict__ ynB,
    u16* __restrict__ mb0, u16* __restrict__ mb1, u16* __restrict__ mb2,
    u16* __restrict__ mb3, u16* __restrict__ mb4, u16* __restrict__ mb5) {
  __shared__ __align__(16) u16 As[64 * 256];   // 32KB, [row][chunk^(row&7)]
  // --- XCD-grouping remap (bijective): lin -> (cblk, yblk, z) with same (yblk,z)'s
  //     4 c-blocks at lin stride 8 (same XCD under round-robin dispatch).
  int lin = blockIdx.x + (blockIdx.y << 2) + (blockIdx.z << 9);
  int xcd = lin & 7, slot = lin >> 3;
  int cblk = slot & 3;
  int yz = xcd * 32 + (slot >> 2);
  int yblk = yz & 127, z = yz >> 7;
  const u16* A  = z ? h2b : h1b;
  const u16* Am = z ? h2mb : h1mb;
  const u16* Wphi = W2dB + (size_t)(z ? 2 : 0) * 65536;
  const u16* Wpsi = W2dB + (size_t)(z ? 3 : 1) * 65536;
  const float* ynphi = ynB + (z ? 512 : 0);
  const float* ynpsi = ynB + (z ? 768 : 256);
  u16* oMiu = z ? mb3 : mb0;
  u16* oPhi = z ? mb4 : mb1;
  u16* oPsi = z ? mb5 : mb2;
  int tid = threadIdx.x;
  int w = tid >> 6, l = tid & 63, r15 = l & 15, g = l >> 4;
  int i0 = yblk * 64;
  int n0 = cblk * 64;
  // stage A tile; source chunk pre-swizzled so LDS[row][c] = G[row][c^(row&7)]
  {
    const u16* Ag = A + (size_t)i0 * 256;
    #pragma unroll
    for (int p = 0; p < 8; ++p) {
      int cidx = p * 256 + tid;            // 16B-chunk slot, 0..2047
      int row = cidx >> 5, c = cidx & 31;
      int gs = (row << 5) + (c ^ (row & 7));
      gload16(Ag + gs * 8, As + cidx * 8);
    }
  }
  __syncthreads();   // drains vmcnt: tile resident
  f32x4 zero = {0.f, 0.f, 0.f, 0.f};
  f32x4 aP[4], aQ[4], aU[4], aD1[4], aD2[4];
  #pragma unroll
  for (int n = 0; n < 4; ++n) { aP[n] = zero; aQ[n] = zero; aU[n] = zero; aD1[n] = zero; aD2[n] = zero; }
  int arow = w * 16 + r15;                 // row in tile
  int rx = arow & 7;
  size_t ambase = (size_t)(i0 + arow) * 256 + g * 8;
  #pragma unroll
  for (int kc = 0; kc < 8; ++kc) {
    int lchunk = arow * 32 + (((kc << 2) + g) ^ rx);
    uint4 xa = *reinterpret_cast<const uint4*>(As + lchunk * 8);
    uint4 xc = *reinterpret_cast<const uint4*>(Am + ambase + kc * 32);
    bf16x8 fa = *reinterpret_cast<const bf16x8*>(&xa);
    bf16x8 fc = *reinterpret_cast<const bf16x8*>(&xc);
    bf16x8 fu, fp, fq;
    float ta, tc;
    ta = bf2f((u16)(xa.x & 0xffff)); tc = bf2f((u16)(xc.x & 0xffff));
    fu[0] = (__bf16)(ta * tc); fp[0] = (__bf16)(ta * ta); fq[0] = (__bf16)(tc * tc);
    ta = bf2f((u16)(xa.x >> 16));    tc = bf2f((u16)(xc.x >> 16));
    fu[1] = (__bf16)(ta * tc); fp[1] = (__bf16)(ta * ta); fq[1] = (__bf16)(tc * tc);
    ta = bf2f((u16)(xa.y & 0xffff)); tc = bf2f((u16)(xc.y & 0xffff));
    fu[2] = (__bf16)(ta * tc); fp[2] = (__bf16)(ta * ta); fq[2] = (__bf16)(tc * tc);
    ta = bf2f((u16)(xa.y >> 16));    tc = bf2f((u16)(xc.y >> 16));
    fu[3] = (__bf16)(ta * tc); fp[3] = (__bf16)(ta * ta); fq[3] = (__bf16)(tc * tc);
    ta = bf2f((u16)(xa.z & 0xffff)); tc = bf2f((u16)(xc.z & 0xffff));
    fu[4] = (__bf16)(ta * tc); fp[4] = (__bf16)(ta * ta); fq[4] = (__bf16)(tc * tc);
    ta = bf2f((u16)(xa.z >> 16));    tc = bf2f((u16)(xc.z >> 16));
    fu[5] = (__bf16)(ta * tc); fp[5] = (__bf16)(ta * ta); fq[5] = (__bf16)(tc * tc);
    ta = bf2f((u16)(xa.w & 0xffff)); tc = bf2f((u16)(xc.w & 0xffff));
    fu[6] = (__bf16)(ta * tc); fp[6] = (__bf16)(ta * ta); fq[6] = (__bf16)(tc * tc);
    ta = bf2f((u16)(xa.w >> 16));    tc = bf2f((u16)(xc.w >> 16));
    fu[7] = (__bf16)(ta * tc); fp[7] = (__bf16)(ta * ta); fq[7] = (__bf16)(tc * tc);
    #pragma unroll
    for (int n = 0; n < 4; ++n) {
      size_t boff = (size_t)(n0 + n * 16 + r15) * 256 + kc * 32 + g * 8;
      bf16x8 bw = *reinterpret_cast<const bf16x8*>(W2t + boff);
      aP[n] = mfma16(fp, bw, aP[n]);
      aQ[n] = mfma16(fq, bw, aQ[n]);
      aU[n] = mfma16(fu, bw, aU[n]);
      bf16x8 b1 = *reinterpret_cast<const bf16x8*>(Wphi + boff);
      aD1[n] = mfma16(fa, b1, aD1[n]);
      bf16x8 b2 = *reinterpret_cast<const bf16x8*>(Wpsi + boff);
      aD2[n] = mfma16(fc, b2, aD2[n]);
    }
  }
  int io = i0 + w * 16 + g * 4;
  #pragma unroll
  for (int n = 0; n < 4; ++n) {
    int c = n0 + n * 16 + r15;
    float y1 = ynphi[c], y2 = ynpsi[c];
    #pragma unroll
    for (int q = 0; q < 4; ++q) {
      float rp = rsqrtf(fmaxf(aP[n][q], 1e-30f));
      float rq = rsqrtf(fmaxf(aQ[n][q], 1e-30f));
      size_t idx = (size_t)(io + q) * 256 + c;
      oMiu[idx] = f2bf(aU[n][q] * rp * rq);
      oPhi[idx] = f2bf(aD1[n][q] * rp * y1);
      oPsi[idx] = f2bf(aD2[n][q] * rq * y2);
    }
  }
}

// ======================= scalar match pair (om1/om2: 1x256 each) =======================
__global__ void k_match_g(const float* __restrict__ X1, const float* __restrict__ Y1,
                          const float* __restrict__ X2, const float* __restrict__ Y2,
                          const float* __restrict__ W2, float* __restrict__ v) {
  __shared__ float u[256], p[256], q[256];
  const float* X = blockIdx.x ? X2 : X1;
  const float* Y = blockIdx.x ? Y2 : Y1;
  float* o = v + (blockIdx.x ? 1792 : 768);
  int t = threadIdx.x;
  float xv = X[t], yv = Y[t];
  u[t] = xv * yv; p[t] = xv * xv; q[t] = yv * yv;
  __syncthreads();
  float a = 0.f, b = 0.f, c = 0.f;
  #pragma unroll 4
  for (int d = 0; d < 256; ++d) {
    float wv = W2[(size_t)d * DDIM + t];
    a += u[d] * wv; b += p[d] * wv; c += q[d] * wv;
  }
  o[t] = a / fmaxf(sqrtf(b) * sqrtf(c), FEPS);
}

__global__ void k_w2(const float* __restrict__ Wm, float* __restrict__ W2, int n) {
  int i = blockIdx.x * blockDim.x + threadIdx.x;
  if (i < n) { float v = Wm[i]; W2[i] = v * v; }
}

// ======================= batched readouts (bf16 inputs) =======================
__global__ void k_bmu_b(PLB L, float* __restrict__ mu) {
  const u16* h = L.p[blockIdx.y];
  int d = threadIdx.x;
  int r0 = blockIdx.x * 128;
  float acc = 0.f;
  for (int r = 0; r < 128; ++r) acc += bf2f(h[(size_t)(r0 + r) * 256 + d]);
  atomicAdd(&mu[blockIdx.y * 256 + d], acc);
}

__global__ void k_bgv(const float* __restrict__ mu, const float* __restrict__ Wr,
                      float* __restrict__ g) {
  __shared__ float ls[256];
  int m = blockIdx.x, t = threadIdx.x;
  ls[t] = mu[m * 256 + t] * (1.f / (float)NN);
  __syncthreads();
  float acc = 0.f;
  #pragma unroll 4
  for (int d = 0; d < 256; ++d) acc += ls[d] * Wr[(size_t)d * 256 + t];
  g[m * 256 + t] = tanhf(acc);
}

__global__ __launch_bounds__(256) void k_bsc_b(PLB L, const float* __restrict__ g,
                                               float* __restrict__ v) {
  __shared__ __align__(16) float gs[256];
  __shared__ float sarr[32];
  int m = blockIdx.y;
  const u16* h = L.p[m];
  int t = threadIdx.x, w = t >> 6, l = t & 63;
  gs[t] = g[m * 256 + t];
  __syncthreads();
  int r0 = blockIdx.x * 32;
  float4 gv4 = reinterpret_cast<const float4*>(gs)[l];
  for (int rr = w * 8; rr < w * 8 + 8; ++rr) {
    ushort4 hv = *reinterpret_cast<const ushort4*>(h + (size_t)(r0 + rr) * 256 + l * 4);
    float dot = bf2f(hv.x) * gv4.x + bf2f(hv.y) * gv4.y + bf2f(hv.z) * gv4.z + bf2f(hv.w) * gv4.w;
    #pragma unroll
    for (int o = 32; o > 0; o >>= 1) dot += __shfl_xor(dot, o);
    if (!l) sarr[rr] = 1.f / (1.f + expf(-dot));
  }
  __syncthreads();
  float acc = 0.f;
  for (int rr = 0; rr < 32; ++rr) acc += sarr[rr] * bf2f(h[(size_t)(r0 + rr) * 256 + t]);
  atomicAdd(&v[L.slot[m] + t], acc);
}

// ======================= MLP (split-K parallel GEMV) =======================
__global__ void k_binit(const float* __restrict__ b1, const float* __restrict__ b2,
                        const float* __restrict__ b3, float* __restrict__ l1,
                        float* __restrict__ l2, float* __restrict__ l3) {
  int t = blockIdx.x * 256 + threadIdx.x;
  if (t < 512) l1[t] = b1[t];
  if (t < 256) l2[t] = b2[t];
  if (t < 128) l3[t] = b3[t];
}

__global__ void k_gemv(const float* __restrict__ vin, const float* __restrict__ w,
                       float* __restrict__ out, int K, int M, int Kc, int relu_in) {
  int m = blockIdx.x * 256 + threadIdx.x;
  if (m >= M) return;
  int k0 = blockIdx.y * Kc;
  float acc = 0.f;
  #pragma unroll 4
  for (int k = k0; k < k0 + Kc; ++k) {
    float x = vin[k];
    if (relu_in) x = fmaxf(x, 0.f);
    acc += x * w[(size_t)k * M + m];
  }
  atomicAdd(&out[m], acc);
}

__global__ void k_final(const float* __restrict__ l3, const float* __restrict__ w4,
                        const float* __restrict__ b4, const int* __restrict__ label,
                        float* __restrict__ out) {
  __shared__ float ls[128];
  int t = threadIdx.x;
  ls[t] = fmaxf(l3[t], 0.f) * w4[t];
  __syncthreads();
  for (int w = 64; w > 0; w >>= 1) { if (t < w) ls[t] += ls[t + w]; __syncthreads(); }
  if (t == 0) {
    float z = 1.f / (1.f + expf(-(ls[0] + b4[0])));
    out[0] = z;
    float lb = (float)label[0];
    out[1] = lb;
    out[2] = expf(-lb);
  }
}

// ======================= host =======================
extern "C" void kernel_launch(void* const* d_in, const int* in_sizes, int n_in,
                              void* d_out, int out_size, void* d_ws, size_t ws_size,
                              hipStream_t stream) {
  (void)in_sizes; (void)n_in; (void)out_size;
  const float* x_s   = (const float*)d_in[0];
  const float* x_t   = (const float*)d_in[1];
  const int*   ei_s  = (const int*)d_in[2];
  const int*   ei_t  = (const int*)d_in[3];
  const int*   label = (const int*)d_in[4];
  const float* W_g1  = (const float*)d_in[5];
  const float* a1s   = (const float*)d_in[6];
  const float* a1d   = (const float*)d_in[7];
  const float* W_g2  = (const float*)d_in[8];
  const float* a2s   = (const float*)d_in[9];
  const float* a2d   = (const float*)d_in[10];
  const float* W_read  = (const float*)d_in[11];
  const float* W_match = (const float*)d_in[12];
  const float* w1 = (const float*)d_in[13]; const float* b1 = (const float*)d_in[14];
  const float* w2 = (const float*)d_in[15]; const float* b2 = (const float*)d_in[16];
  const float* w3 = (const float*)d_in[17]; const float* b3 = (const float*)d_in[18];
  const float* w4 = (const float*)d_in[19]; const float* b4 = (const float*)d_in[20];
  float* out = (float*)d_out;

  char* base = (char*)d_ws;
  size_t off = 0;
  auto alloc = [&](size_t bytes) -> void* {
    void* pp = base + off;
    off = (off + bytes + 255) & ~(size_t)255;
    return pp;
  };
  double* dsum = (double*)alloc(4 * sizeof(double));
  u16*   gb   = (u16*)alloc((size_t)NN * HH * 2);
  u16*   h2pb = (u16*)alloc((size_t)NN * DDIM * 2);
  u16*   aggfb= (u16*)alloc((size_t)NN * FF * 2);
  float* h1   = (float*)alloc((size_t)NN * DDIM * 4);
  float* h2   = (float*)alloc((size_t)NN * DDIM * 4);
  u16*   f1b  = (u16*)alloc((size_t)NN * FF * 2);
  u16*   f2b  = (u16*)alloc((size_t)NN * FF * 2);
  u16*   h1b  = (u16*)alloc((size_t)NN * DDIM * 2);
  u16*   h2b  = (u16*)alloc((size_t)NN * DDIM * 2);
  u16*   h1mb = (u16*)alloc((size_t)NN * DDIM * 2);
  u16*   h2mb = (u16*)alloc((size_t)NN * DDIM * 2);
  u16*   h1t  = (u16*)alloc((size_t)NN * DDIM * 2);
  u16*   h2t  = (u16*)alloc((size_t)NN * DDIM * 2);
  u16*   wh1t = (u16*)alloc((size_t)NN * DDIM * 2);
  u16*   wh2t = (u16*)alloc((size_t)NN * DDIM * 2);
  u16*   mb0  = (u16*)alloc((size_t)NN * DDIM * 2);
  u16*   mb1  = (u16*)alloc((size_t)NN * DDIM * 2);
  u16*   mb2  = (u16*)alloc((size_t)NN * DDIM * 2);
  u16*   mb3  = (u16*)alloc((size_t)NN * DDIM * 2);
  u16*   mb4  = (u16*)alloc((size_t)NN * DDIM * 2);
  u16*   mb5  = (u16*)alloc((size_t)NN * DDIM * 2);
  float* alpha= (float*)alloc((size_t)ET * 4);
  int*   srcs = (int*)alloc((size_t)ET * 4);
  int*   deg  = (int*)alloc(NN * 4);
  int*   curs = (int*)alloc(NN * 4);
  int*   offs = (int*)alloc((NN + 1) * 4);
  float* n1inv= (float*)alloc(NN * 4);
  float* n2inv= (float*)alloc(NN * 4);
  float* Rr   = (float*)alloc(NN * 4);
  float* Ss   = (float*)alloc(NN * 4);
  float* scj1 = (float*)alloc(NN * 4);
  float* scj2 = (float*)alloc(NN * 4);
  float* hsb  = (float*)alloc(NN * 4);
  float* hdb  = (float*)alloc(NN * 4);
  float* W2   = (float*)alloc((size_t)DDIM * DDIM * 4);
  u16*   Wg1t = (u16*)alloc((size_t)HH * FF * 2);
  u16*   Wg2t = (u16*)alloc((size_t)DDIM * HH * 2);
  u16*   W2t  = (u16*)alloc((size_t)DDIM * DDIM * 2);
  u16*   W2dB = (u16*)alloc(4 * 65536 * 2);
  float* ynB  = (float*)alloc(4 * 256 * 4);
  u16*   Mb   = (u16*)alloc(2 * 65536 * 2);
  float* wa   = (float*)alloc(1280 * 4);
  float* mug1 = (float*)alloc(4 * 256 * 4);
  float* ogs  = (float*)alloc(4 * 256 * 4);
  float* mug2 = (float*)alloc(6 * 256 * 4);
  float* v    = (float*)alloc(2048 * 4);
  float* ut   = (float*)alloc(512 * 4);
  float* Mf   = (float*)alloc(2 * 65536 * 4);
  float* g1   = (float*)alloc(4 * 256 * 4);
  float* g2   = (float*)alloc(6 * 256 * 4);
  float* l1o  = (float*)alloc(512 * 4);
  float* l2o  = (float*)alloc(256 * 4);
  float* l3o  = (float*)alloc(128 * 4);
  if (off > ws_size) return;

  float* h1g  = ogs + 0;
  float* h2g  = ogs + 256;
  float* h1mg = ogs + 512;
  float* h2mg = ogs + 768;
  const size_t zr_bytes = (4 * 256 + 4 * 256 + 6 * 256 + 2048 + 512 + 2 * 65536) * 4;

  // ---- stage 0 ----
  hipMemsetAsync(dsum, 0, 4 * sizeof(double), stream);
  k_reduce2<<<dim3(1024, 2), 256, 0, stream>>>(x_s, x_t, NN * FF, dsum);
  k_normalize2<<<dim3(1024, 2), 256, 0, stream>>>(x_s, x_t, f1b, f2b, NN * FF, dsum);

  // ---- weight preps ----
  k_tr_bf16<<<dim3(HH / 32, FF / 32), 256, 0, stream>>>(W_g1, Wg1t, FF, HH, 0);
  k_tr_bf16<<<dim3(DDIM / 32, HH / 32), 256, 0, stream>>>(W_g2, Wg2t, HH, DDIM, 0);
  k_tr_bf16<<<dim3(DDIM / 32, DDIM / 32), 256, 0, stream>>>(W_match, W2t, DDIM, DDIM, 1);
  k_w2<<<dim3((DDIM * DDIM + 255) / 256), 256, 0, stream>>>(W_match, W2, DDIM * DDIM);
  k_wa<<<dim3(2), 256, 0, stream>>>(W_g1, a1s, a1d, W_g2, a2s, a2d, wa);

  // ---- GAT ----
  auto run_gat = [&](const u16* finb, const int* ei, float* hout, u16* houtb) {
    hipMemsetAsync(deg, 0, NN * 4, stream);
    k_hist<<<dim3((ET + 255) / 256), 256, 0, stream>>>(ei, deg);
    k_scan<<<1, 256, 0, stream>>>(deg, offs, curs);
    k_scatter<<<dim3((ET + 255) / 256), 256, 0, stream>>>(ei, curs, srcs);
    k_dots1<<<dim3(NN / 4), 256, 0, stream>>>(finb, wa, hsb, hdb);
    k_alpha<<<dim3(NN / 4), 256, 0, stream>>>(offs, srcs, hsb, hdb, alpha);
    k_aggf<<<dim3(NN / 4), 256, 0, stream>>>(offs, srcs, alpha, finb, aggfb);
    hipMemsetAsync(hsb, 0, 2 * NN * 4, stream);
    k_gemm_bf<<<dim3(HH / 128, NN / 64), 256, 0, stream>>>(aggfb, Wg1t, gb, FF, HH, 1,
                                                           wa + 256, wa + 768, hsb, hdb);
    k_alpha<<<dim3(NN / 4), 256, 0, stream>>>(offs, srcs, hsb, hdb, alpha);
    k_gemm_bf<<<dim3(DDIM / 128, NN / 64), 256, 0, stream>>>(gb, Wg2t, h2pb, HH, DDIM, 0,
                                                             nullptr, nullptr, nullptr, nullptr);
    k_agg3<<<dim3(NN / 4), 256, 0, stream>>>(offs, srcs, alpha, h2pb, hout, houtb);
  };
  run_gat(f1b, ei_s, h1, h1b);
  run_gat(f2b, ei_t, h2, h2b);

  // ---- mutual (rank-256 collapse) ----
  k_rninv2<<<dim3(NN / 4, 2), 256, 0, stream>>>(h1, h2, n1inv, n2inv);
  hipMemsetAsync(mug1, 0, zr_bytes, stream);
  k_wsum<<<dim3(64, 2), 256, 0, stream>>>(h1, h2, n1inv, n2inv, ut);
  k_rs<<<dim3(NN / 4, 2), 256, 0, stream>>>(h1, h2, n1inv, n2inv, ut, Rr, Ss);
  k_scj<<<dim3(NN / 256), 256, 0, stream>>>(Ss, Rr, n1inv, n2inv, scj1, scj2);
  k_tr2w<<<dim3(DDIM / 32, NN / 32, 2), 256, 0, stream>>>(h2, scj1, h2t, wh2t, h1, scj2, h1t, wh1t);
  k_gemm_M<<<dim3(2, 4, 32), 256, 0, stream>>>(wh2t, h2t, wh1t, h1t, Mf);
  k_m2bf<<<dim3(256, 2), 256, 0, stream>>>(Mf, Mb);
  k_gemm_hm<<<dim3(2, 128, 2), 256, 0, stream>>>(h1b, Mb, n1inv, h1mb,
                                                 h2b, Mb + 65536, n2inv, h2mb);

  // ---- readout group 1: h1, h2, h1m, h2m (bf16) ----
  PLB g1l;
  g1l.p[0] = h1b;  g1l.slot[0] = 0;
  g1l.p[1] = h2b;  g1l.slot[1] = 256;
  g1l.p[2] = h1mb; g1l.slot[2] = 512;
  g1l.p[3] = h2mb; g1l.slot[3] = 768;
  k_bmu_b<<<dim3(64, 4), 256, 0, stream>>>(g1l, mug1);
  k_bgv<<<dim3(4), 256, 0, stream>>>(mug1, W_read, g1);
  k_bsc_b<<<dim3(256, 4), 256, 0, stream>>>(g1l, g1, ogs);

  // ---- matches (fused 5-chain kernel, LDS-staged A, XCD-grouped) ----
  k_w2d<<<dim3(256, 4), 256, 0, stream>>>(W2t, ogs, W2dB, ynB);
  k_match5<<<dim3(4, 128, 2), 256, 0, stream>>>(h1b, h1mb, h2b, h2mb, W2t, W2dB, ynB,
                                                mb0, mb1, mb2, mb3, mb4, mb5);
  k_match_g<<<dim3(2), 256, 0, stream>>>(h1g, h1mg, h2g, h2mg, W2, v);

  // ---- readout group 2: 6 bf16 match outputs -> v slots ----
  PLB g2l;
  g2l.p[0] = mb0; g2l.slot[0] = 0;
  g2l.p[1] = mb1; g2l.slot[1] = 256;
  g2l.p[2] = mb2; g2l.slot[2] = 512;
  g2l.p[3] = mb3; g2l.slot[3] = 1024;
  g2l.p[4] = mb4; g2l.slot[4] = 1280;
  g2l.p[5] = mb5; g2l.slot[5] = 1536;
  k_bmu_b<<<dim3(64, 6), 256, 0, stream>>>(g2l, mug2);
  k_bgv<<<dim3(6), 256, 0, stream>>>(mug2, W_read, g2);
  k_bsc_b<<<dim3(256, 6), 256, 0, stream>>>(g2l, g2, v);

  // ---- MLP (split-K gemv) ----
  k_binit<<<dim3(2), 256, 0, stream>>>(b1, b2, b3, l1o, l2o, l3o);
  k_gemv<<<dim3(2, 16), 256, 0, stream>>>(v, w1, l1o, 2048, 512, 128, 0);
  k_gemv<<<dim3(1, 8), 256, 0, stream>>>(l1o, w2, l2o, 512, 256, 64, 1);
  k_gemv<<<dim3(1, 8), 256, 0, stream>>>(l2o, w3, l3o, 256, 128, 32, 1);
  k_final<<<1, 128, 0, stream>>>(l3o, w4, b4, label, out);
}

// Round 15
// 636.447 us; speedup vs baseline: 1.0073x; 1.0073x over previous
//
#include <hip/hip_runtime.h>
#include <hip/hip_bf16.h>
#include <math.h>
#include <stddef.h>

#define NN 8192
#define FF 128
#define HH 512
#define DDIM 256
#define EE 131072
#define ET (2*EE + NN)     // 270336 edges after symmetrize + self loops
#define FEPS 1e-8f

typedef float f32x4 __attribute__((ext_vector_type(4)));
typedef __bf16 bf16x8 __attribute__((ext_vector_type(8)));
typedef unsigned short u16;

static __device__ __forceinline__ u16 f2bf(float f) {
  union { float f; unsigned u; } v; v.f = f;
  return (u16)((v.u + 0x7fffu + ((v.u >> 16) & 1u)) >> 16);
}
static __device__ __forceinline__ float bf2f(u16 h) {
  union { unsigned u; float f; } v; v.u = ((unsigned)h) << 16;
  return v.f;
}
static __device__ __forceinline__ f32x4 mfma16(bf16x8 a, bf16x8 b, f32x4 c) {
  return __builtin_amdgcn_mfma_f32_16x16x32_bf16(a, b, c, 0, 0, 0);
}
// async global->LDS, 16B per lane.
static __device__ __forceinline__ void gload16(const void* g, void* lds) {
  __builtin_amdgcn_global_load_lds(
      (const __attribute__((address_space(1))) void*)(unsigned long long)(uintptr_t)g,
      (__attribute__((address_space(3))) void*)(unsigned int)(uintptr_t)lds,
      16, 0, 0);
}

struct PLB { const u16* p[6]; int slot[6]; };

// ======================= stage 0: global mean/std normalize (fused pair) =======================
__global__ void k_reduce2(const float* __restrict__ xa, const float* __restrict__ xb,
                          int n, double* __restrict__ out) {
  const float* x = blockIdx.y ? xb : xa;
  double* o = out + 2 * blockIdx.y;
  __shared__ double s1[256], s2[256];
  double a = 0.0, b = 0.0;
  for (int i = blockIdx.x * blockDim.x + threadIdx.x; i < n; i += gridDim.x * blockDim.x) {
    double v = (double)x[i];
    a += v; b += v * v;
  }
  s1[threadIdx.x] = a; s2[threadIdx.x] = b;
  __syncthreads();
  for (int w = 128; w > 0; w >>= 1) {
    if (threadIdx.x < w) { s1[threadIdx.x] += s1[threadIdx.x + w]; s2[threadIdx.x] += s2[threadIdx.x + w]; }
    __syncthreads();
  }
  if (threadIdx.x == 0) { atomicAdd(&o[0], s1[0]); atomicAdd(&o[1], s2[0]); }
}

__global__ void k_normalize2(const float* __restrict__ xa, const float* __restrict__ xb,
                             u16* __restrict__ ya, u16* __restrict__ yb, int n,
                             const double* __restrict__ s) {
  const float* x = blockIdx.y ? xb : xa;
  u16* y = blockIdx.y ? yb : ya;
  const double* sp = s + 2 * blockIdx.y;
  double mean = sp[0] / (double)n;
  double var = (sp[1] - (double)n * mean * mean) / (double)(n - 1);  // ddof=1
  float mu = (float)mean;
  float inv = (float)(1.0 / sqrt(var));
  for (int i = blockIdx.x * blockDim.x + threadIdx.x; i < n; i += gridDim.x * blockDim.x)
    y[i] = f2bf((x[i] - mu) * inv);
}

// ======================= GAT: CSR build =======================
__global__ void k_hist(const int* __restrict__ ei, int* __restrict__ deg) {
  int t = blockIdx.x * blockDim.x + threadIdx.x;
  if (t >= ET) return;
  int dst = (t < EE) ? ei[EE + t] : ((t < 2*EE) ? ei[t - EE] : (t - 2*EE));
  atomicAdd(&deg[dst], 1);
}

__global__ void k_scan(const int* __restrict__ deg, int* __restrict__ offs, int* __restrict__ cursor) {
  __shared__ int ts[256];
  int tid = threadIdx.x;
  int loc[32];
  int s = 0;
  #pragma unroll
  for (int i = 0; i < 32; ++i) { loc[i] = s; s += deg[tid * 32 + i]; }
  ts[tid] = s;
  __syncthreads();
  for (int off = 1; off < 256; off <<= 1) {
    int v = (tid >= off) ? ts[tid - off] : 0;
    __syncthreads();
    ts[tid] += v;
    __syncthreads();
  }
  int pre = ts[tid] - s;
  #pragma unroll
  for (int i = 0; i < 32; ++i) {
    int o = pre + loc[i];
    offs[tid * 32 + i] = o;
    cursor[tid * 32 + i] = o;
  }
  if (tid == 255) offs[NN] = ts[255];
}

__global__ void k_scatter(const int* __restrict__ ei, int* __restrict__ cursor, int* __restrict__ srcs) {
  int t = blockIdx.x * blockDim.x + threadIdx.x;
  if (t >= ET) return;
  int src = (t < 2*EE) ? ei[t] : (t - 2*EE);
  int dst = (t < EE) ? ei[EE + t] : ((t < 2*EE) ? ei[t - EE] : (t - 2*EE));
  int pos = atomicAdd(&cursor[dst], 1);
  srcs[pos] = src;
}

// ======================= transpose f32 -> bf16 (optionally squared) =======================
__global__ __launch_bounds__(256) void k_tr_bf16(const float* __restrict__ src, u16* __restrict__ dst,
                                                 int R, int C, int sq) {
  __shared__ float T[32][33];
  int tx = threadIdx.x & 31, ty = threadIdx.x >> 5;
  int r0 = blockIdx.y * 32, c0 = blockIdx.x * 32;
  #pragma unroll
  for (int p = 0; p < 4; ++p)
    T[ty + 8 * p][tx] = src[(size_t)(r0 + ty + 8 * p) * C + c0 + tx];
  __syncthreads();
  #pragma unroll
  for (int p = 0; p < 4; ++p) {
    float v = T[tx][ty + 8 * p];
    if (sq) v *= v;
    dst[(size_t)(c0 + ty + 8 * p) * R + r0 + tx] = f2bf(v);
  }
}

// fused pair transpose+scale
__global__ __launch_bounds__(256) void k_tr2w(const float* __restrict__ hA, const float* __restrict__ scA,
                                              u16* __restrict__ tA, u16* __restrict__ wA,
                                              const float* __restrict__ hB, const float* __restrict__ scB,
                                              u16* __restrict__ tB, u16* __restrict__ wB) {
  __shared__ float T[32][33];
  __shared__ float W[32][33];
  const float* src = blockIdx.z ? hB : hA;
  const float* sc  = blockIdx.z ? scB : scA;
  u16* dt = blockIdx.z ? tB : tA;
  u16* dw = blockIdx.z ? wB : wA;
  int tx = threadIdx.x & 31, ty = threadIdx.x >> 5;
  int r0 = blockIdx.y * 32, c0 = blockIdx.x * 32;
  #pragma unroll
  for (int p = 0; p < 4; ++p) {
    int j = r0 + ty + 8 * p;
    float v = src[(size_t)j * DDIM + c0 + tx];
    T[ty + 8 * p][tx] = v;
    W[ty + 8 * p][tx] = v * sc[j];
  }
  __syncthreads();
  #pragma unroll
  for (int p = 0; p < 4; ++p) {
    size_t o = (size_t)(c0 + ty + 8 * p) * NN + r0 + tx;
    dt[o] = f2bf(T[tx][ty + 8 * p]);
    dw[o] = f2bf(W[tx][ty + 8 * p]);
  }
}

// ======================= wa: attention vectors pulled through the GAT weights =======================
__global__ void k_wa(const float* __restrict__ Wg1, const float* __restrict__ a1s,
                     const float* __restrict__ a1d, const float* __restrict__ Wg2,
                     const float* __restrict__ a2s, const float* __restrict__ a2d,
                     float* __restrict__ wa) {
  int t = threadIdx.x;
  if (blockIdx.x == 0) {
    if (t < 128) {
      float s = 0.f, d = 0.f;
      for (int j = 0; j < 512; ++j) { float w = Wg1[(size_t)t * 512 + j]; s += w * a1s[j]; d += w * a1d[j]; }
      wa[t] = s; wa[128 + t] = d;
    }
  } else {
    for (int k = t; k < 512; k += 256) {
      float s = 0.f, d = 0.f;
      for (int j = 0; j < 256; ++j) { float w = Wg2[(size_t)k * 256 + j]; s += w * a2s[j]; d += w * a2d[j]; }
      wa[256 + k] = s; wa[768 + k] = d;
    }
  }
}

// dots over raw features (D=128)
__global__ void k_dots1(const u16* __restrict__ fb, const float* __restrict__ wa,
                        float* __restrict__ hs, float* __restrict__ hd) {
  int wid = (blockIdx.x * blockDim.x + threadIdx.x) >> 6;
  int lane = threadIdx.x & 63;
  if (wid >= NN) return;
  unsigned v = *reinterpret_cast<const unsigned*>(fb + (size_t)wid * 128 + lane * 2);
  float f0 = bf2f((u16)(v & 0xffff)), f1 = bf2f((u16)(v >> 16));
  float2 ws = *reinterpret_cast<const float2*>(wa + lane * 2);
  float2 wd = *reinterpret_cast<const float2*>(wa + 128 + lane * 2);
  float s = f0 * ws.x + f1 * ws.y;
  float d = f0 * wd.x + f1 * wd.y;
  #pragma unroll
  for (int o = 32; o > 0; o >>= 1) { s += __shfl_xor(s, o); d += __shfl_xor(d, o); }
  if (!lane) { hs[wid] = s; hd[wid] = d; }
}

// ======================= MFMA GEMM with optional ELU + fused attention-dot epilogue ==============
__global__ __launch_bounds__(256) void k_gemm_bf(const u16* __restrict__ A, const u16* __restrict__ Bt,
                                                 u16* __restrict__ Cb, int K, int N, int elu,
                                                 const float* __restrict__ as_, const float* __restrict__ ad_,
                                                 float* __restrict__ hs, float* __restrict__ hd) {
  int w = threadIdx.x >> 6, l = threadIdx.x & 63, r15 = l & 15, g = l >> 4;
  int i0 = blockIdx.y * 64 + w * 16;
  int n0 = blockIdx.x * 128;
  f32x4 zero = {0.f, 0.f, 0.f, 0.f};
  f32x4 acc[8];
  #pragma unroll
  for (int n = 0; n < 8; ++n) acc[n] = zero;
  int kcN = K >> 5;
  const u16* arow = A + (size_t)(i0 + r15) * K + g * 8;
  for (int kc = 0; kc < kcN; ++kc) {
    bf16x8 a = *reinterpret_cast<const bf16x8*>(arow + kc * 32);
    #pragma unroll
    for (int n = 0; n < 8; ++n) {
      bf16x8 b = *reinterpret_cast<const bf16x8*>(Bt + (size_t)(n0 + n * 16 + r15) * K + kc * 32 + g * 8);
      acc[n] = mfma16(a, b, acc[n]);
    }
  }
  if (elu) {
    #pragma unroll
    for (int n = 0; n < 8; ++n)
      #pragma unroll
      for (int q = 0; q < 4; ++q)
        acc[n][q] = acc[n][q] > 0.f ? acc[n][q] : (expf(acc[n][q]) - 1.f);
  }
  int io = i0 + g * 4;
  #pragma unroll
  for (int n = 0; n < 8; ++n) {
    int c = n0 + n * 16 + r15;
    #pragma unroll
    for (int q = 0; q < 4; ++q)
      Cb[(size_t)(io + q) * N + c] = f2bf(acc[n][q]);
  }
  if (as_) {
    float hsum[4] = {0.f, 0.f, 0.f, 0.f}, dsum[4] = {0.f, 0.f, 0.f, 0.f};
    #pragma unroll
    for (int n = 0; n < 8; ++n) {
      int c = n0 + n * 16 + r15;
      float av = as_[c], dv = ad_[c];
      #pragma unroll
      for (int q = 0; q < 4; ++q) { hsum[q] += acc[n][q] * av; dsum[q] += acc[n][q] * dv; }
    }
    #pragma unroll
    for (int q = 0; q < 4; ++q) {
      #pragma unroll
      for (int o = 1; o < 16; o <<= 1) { hsum[q] += __shfl_xor(hsum[q], o); dsum[q] += __shfl_xor(dsum[q], o); }
    }
    if (r15 == 0) {
      #pragma unroll
      for (int q = 0; q < 4; ++q) {
        atomicAdd(&hs[io + q], hsum[q]);
        atomicAdd(&hd[io + q], dsum[q]);
      }
    }
  }
}

// ======================= GAT: attention (unrolled gathers) =======================
__global__ void k_alpha(const int* __restrict__ offs, const int* __restrict__ srcs,
                        const float* __restrict__ hs, const float* __restrict__ hd,
                        float* __restrict__ alpha) {
  int wid = (blockIdx.x * blockDim.x + threadIdx.x) >> 6;
  int lane = threadIdx.x & 63;
  if (wid >= NN) return;
  int b = offs[wid], e = offs[wid + 1];
  float hdn = hd[wid];
  float m = -3.4e38f;
  {
    int p = b + lane;
    for (; p + 192 < e; p += 256) {
      int s0 = srcs[p], s1 = srcs[p + 64], s2 = srcs[p + 128], s3 = srcs[p + 192];
      float v0 = hs[s0] + hdn, v1 = hs[s1] + hdn, v2 = hs[s2] + hdn, v3 = hs[s3] + hdn;
      v0 = v0 > 0.f ? v0 : 0.2f * v0; v1 = v1 > 0.f ? v1 : 0.2f * v1;
      v2 = v2 > 0.f ? v2 : 0.2f * v2; v3 = v3 > 0.f ? v3 : 0.2f * v3;
      alpha[p] = v0; alpha[p + 64] = v1; alpha[p + 128] = v2; alpha[p + 192] = v3;
      m = fmaxf(m, fmaxf(fmaxf(v0, v1), fmaxf(v2, v3)));
    }
    for (; p < e; p += 64) {
      float v = hs[srcs[p]] + hdn;
      v = v > 0.f ? v : 0.2f * v;
      alpha[p] = v;
      m = fmaxf(m, v);
    }
  }
  #pragma unroll
  for (int o = 32; o > 0; o >>= 1) m = fmaxf(m, __shfl_xor(m, o));
  float den = 0.f;
  for (int p = b + lane; p < e; p += 64) {
    float ex = expf(alpha[p] - m);
    alpha[p] = ex;
    den += ex;
  }
  #pragma unroll
  for (int o = 32; o > 0; o >>= 1) den += __shfl_xor(den, o);
  float sc = 1.f / (den + 1e-16f);
  for (int p = b + lane; p < e; p += 64) alpha[p] *= sc;
}

// aggregate raw features (D=128), wave per node, x4 unrolled gathers
__global__ __launch_bounds__(256) void k_aggf(const int* __restrict__ offs, const int* __restrict__ srcs,
                                              const float* __restrict__ alpha, const u16* __restrict__ fb,
                                              u16* __restrict__ aggout) {
  int wv = threadIdx.x >> 6, lane = threadIdx.x & 63;
  int n = blockIdx.x * 4 + wv;
  int b = offs[n], e = offs[n + 1];
  float a0 = 0.f, a1 = 0.f;
  const u16* base = fb + lane * 2;
  int p = b;
  for (; p + 4 <= e; p += 4) {
    int s0 = srcs[p], s1 = srcs[p + 1], s2 = srcs[p + 2], s3 = srcs[p + 3];
    float w0 = alpha[p], w1 = alpha[p + 1], w2 = alpha[p + 2], w3 = alpha[p + 3];
    unsigned v0 = *reinterpret_cast<const unsigned*>(base + (size_t)s0 * 128);
    unsigned v1 = *reinterpret_cast<const unsigned*>(base + (size_t)s1 * 128);
    unsigned v2 = *reinterpret_cast<const unsigned*>(base + (size_t)s2 * 128);
    unsigned v3 = *reinterpret_cast<const unsigned*>(base + (size_t)s3 * 128);
    a0 += w0 * bf2f((u16)(v0 & 0xffff)) + w1 * bf2f((u16)(v1 & 0xffff)) +
          w2 * bf2f((u16)(v2 & 0xffff)) + w3 * bf2f((u16)(v3 & 0xffff));
    a1 += w0 * bf2f((u16)(v0 >> 16)) + w1 * bf2f((u16)(v1 >> 16)) +
          w2 * bf2f((u16)(v2 >> 16)) + w3 * bf2f((u16)(v3 >> 16));
  }
  for (; p < e; ++p) {
    float a = alpha[p];
    unsigned v = *reinterpret_cast<const unsigned*>(base + (size_t)srcs[p] * 128);
    a0 += a * bf2f((u16)(v & 0xffff));
    a1 += a * bf2f((u16)(v >> 16));
  }
  unsigned o = ((unsigned)f2bf(a1) << 16) | (unsigned)f2bf(a0);
  *reinterpret_cast<unsigned*>(aggout + (size_t)n * 128 + lane * 2) = o;
}

// aggregate projected layer-2 features (D=256), wave per node, x4 unrolled gathers
__global__ __launch_bounds__(256) void k_agg3(const int* __restrict__ offs, const int* __restrict__ srcs,
                                              const float* __restrict__ alpha, const u16* __restrict__ Hb,
                                              float* __restrict__ outF, u16* __restrict__ outB) {
  int wv = threadIdx.x >> 6, lane = threadIdx.x & 63;
  int n = blockIdx.x * 4 + wv;
  int b = offs[n], e = offs[n + 1];
  float acc[4];
  #pragma unroll
  for (int j = 0; j < 4; ++j) acc[j] = 0.f;
  const u16* base = Hb + lane * 4;
  int p = b;
  for (; p + 4 <= e; p += 4) {
    int s0 = srcs[p], s1 = srcs[p + 1], s2 = srcs[p + 2], s3 = srcs[p + 3];
    float w0 = alpha[p], w1 = alpha[p + 1], w2 = alpha[p + 2], w3 = alpha[p + 3];
    uint2 v0 = *reinterpret_cast<const uint2*>(base + (size_t)s0 * 256);
    uint2 v1 = *reinterpret_cast<const uint2*>(base + (size_t)s1 * 256);
    uint2 v2 = *reinterpret_cast<const uint2*>(base + (size_t)s2 * 256);
    uint2 v3 = *reinterpret_cast<const uint2*>(base + (size_t)s3 * 256);
    acc[0] += w0 * bf2f((u16)(v0.x & 0xffff)) + w1 * bf2f((u16)(v1.x & 0xffff)) +
              w2 * bf2f((u16)(v2.x & 0xffff)) + w3 * bf2f((u16)(v3.x & 0xffff));
    acc[1] += w0 * bf2f((u16)(v0.x >> 16)) + w1 * bf2f((u16)(v1.x >> 16)) +
              w2 * bf2f((u16)(v2.x >> 16)) + w3 * bf2f((u16)(v3.x >> 16));
    acc[2] += w0 * bf2f((u16)(v0.y & 0xffff)) + w1 * bf2f((u16)(v1.y & 0xffff)) +
              w2 * bf2f((u16)(v2.y & 0xffff)) + w3 * bf2f((u16)(v3.y & 0xffff));
    acc[3] += w0 * bf2f((u16)(v0.y >> 16)) + w1 * bf2f((u16)(v1.y >> 16)) +
              w2 * bf2f((u16)(v2.y >> 16)) + w3 * bf2f((u16)(v3.y >> 16));
  }
  for (; p < e; ++p) {
    float a = alpha[p];
    uint2 v = *reinterpret_cast<const uint2*>(base + (size_t)srcs[p] * 256);
    acc[0] += a * bf2f((u16)(v.x & 0xffff)); acc[1] += a * bf2f((u16)(v.x >> 16));
    acc[2] += a * bf2f((u16)(v.y & 0xffff)); acc[3] += a * bf2f((u16)(v.y >> 16));
  }
  float4 of = {acc[0], acc[1], acc[2], acc[3]};
  *reinterpret_cast<float4*>(outF + (size_t)n * 256 + lane * 4) = of;
  ushort4 ob;
  ob.x = f2bf(acc[0]); ob.y = f2bf(acc[1]); ob.z = f2bf(acc[2]); ob.w = f2bf(acc[3]);
  *reinterpret_cast<ushort4*>(outB + (size_t)n * 256 + lane * 4) = ob;
}

// ======================= mutual: inverse row norms (fused pair) =======================
__global__ void k_rninv2(const float* __restrict__ h1, const float* __restrict__ h2,
                         float* __restrict__ o1, float* __restrict__ o2) {
  const float* h = blockIdx.y ? h2 : h1;
  float* o = blockIdx.y ? o2 : o1;
  int wid = (blockIdx.x * blockDim.x + threadIdx.x) >> 6;
  int lane = threadIdx.x & 63;
  if (wid >= NN) return;
  float4 v = *reinterpret_cast<const float4*>(h + (size_t)wid * DDIM + lane * 4);
  float a = v.x * v.x + v.y * v.y + v.z * v.z + v.w * v.w;
  #pragma unroll
  for (int o2_ = 32; o2_ > 0; o2_ >>= 1) a += __shfl_xor(a, o2_);
  if (!lane) o[wid] = 1.f / sqrtf(a);
}

// ======================= mutual rank-1 sums =======================
__global__ void k_wsum(const float* __restrict__ h1, const float* __restrict__ h2,
                       const float* __restrict__ n1inv, const float* __restrict__ n2inv,
                       float* __restrict__ ut) {
  const float* h = blockIdx.y ? h2 : h1;
  const float* wv = blockIdx.y ? n2inv : n1inv;
  float* o = ut + 256 * blockIdx.y;
  int d = threadIdx.x;
  int r0 = blockIdx.x * 128;
  float acc = 0.f;
  for (int r = 0; r < 128; ++r) acc += wv[r0 + r] * h[(size_t)(r0 + r) * 256 + d];
  atomicAdd(&o[d], acc);
}

__global__ void k_rs(const float* __restrict__ h1, const float* __restrict__ h2,
                     const float* __restrict__ n1inv, const float* __restrict__ n2inv,
                     const float* __restrict__ ut, float* __restrict__ R, float* __restrict__ S) {
  const float* h  = blockIdx.y ? h2 : h1;
  const float* ni = blockIdx.y ? n2inv : n1inv;
  const float* gv = blockIdx.y ? ut : ut + 256;
  float* o = blockIdx.y ? S : R;
  int wid = (blockIdx.x * blockDim.x + threadIdx.x) >> 6;
  int lane = threadIdx.x & 63;
  if (wid >= NN) return;
  float4 v = *reinterpret_cast<const float4*>(h + (size_t)wid * 256 + lane * 4);
  float4 g4 = *reinterpret_cast<const float4*>(gv + lane * 4);
  float a = v.x * g4.x + v.y * g4.y + v.z * g4.z + v.w * g4.w;
  #pragma unroll
  for (int o2_ = 32; o2_ > 0; o2_ >>= 1) a += __shfl_xor(a, o2_);
  if (!lane) o[wid] = ni[wid] * a;
}

__global__ void k_scj(const float* __restrict__ S, const float* __restrict__ R,
                      const float* __restrict__ n1inv, const float* __restrict__ n2inv,
                      float* __restrict__ scj1, float* __restrict__ scj2) {
  int j = blockIdx.x * blockDim.x + threadIdx.x;
  if (j >= NN) return;
  scj1[j] = n2inv[j] / S[j];
  scj2[j] = n1inv[j] / R[j];
}

// ======================= M = h^T diag(w) h  (256x256, split-K MFMA) =======================
__global__ __launch_bounds__(256) void k_gemm_M(const u16* __restrict__ A1, const u16* __restrict__ B1,
                                                const u16* __restrict__ A2, const u16* __restrict__ B2,
                                                float* __restrict__ Mf) {
  int mat = blockIdx.z & 1, kch = blockIdx.z >> 1;
  const u16* A = mat ? A2 : A1;
  const u16* Bt = mat ? B2 : B1;
  float* C = Mf + mat * 65536;
  int w = threadIdx.x >> 6, l = threadIdx.x & 63, r15 = l & 15, g = l >> 4;
  int i0 = blockIdx.y * 64 + w * 16;
  int n0 = blockIdx.x * 128;
  f32x4 zero = {0.f, 0.f, 0.f, 0.f};
  f32x4 acc[8];
  #pragma unroll
  for (int n = 0; n < 8; ++n) acc[n] = zero;
  const u16* arow = A + (size_t)(i0 + r15) * NN + g * 8;
  for (int kc = kch * 16; kc < kch * 16 + 16; ++kc) {
    bf16x8 a = *reinterpret_cast<const bf16x8*>(arow + kc * 32);
    #pragma unroll
    for (int n = 0; n < 8; ++n) {
      bf16x8 b = *reinterpret_cast<const bf16x8*>(Bt + (size_t)(n0 + n * 16 + r15) * NN + kc * 32 + g * 8);
      acc[n] = mfma16(a, b, acc[n]);
    }
  }
  int io = i0 + g * 4;
  #pragma unroll
  for (int n = 0; n < 8; ++n) {
    int c = n0 + n * 16 + r15;
    #pragma unroll
    for (int q = 0; q < 4; ++q)
      atomicAdd(&C[(size_t)(io + q) * 256 + c], acc[n][q]);
  }
}

__global__ void k_m2bf(const float* __restrict__ Mf, u16* __restrict__ Mb) {
  size_t o = (size_t)blockIdx.y * 65536 + blockIdx.x * 256 + threadIdx.x;
  Mb[o] = f2bf(Mf[o]);
}

// ======================= hXm = diag(sc) * (hXb @ M^T) -> bf16 =======================
__global__ __launch_bounds__(256) void k_gemm_hm(const u16* __restrict__ A1, const u16* __restrict__ M1,
                                                 const float* __restrict__ s1, u16* __restrict__ O1,
                                                 const u16* __restrict__ A2, const u16* __restrict__ M2,
                                                 const float* __restrict__ s2, u16* __restrict__ O2) {
  int z = blockIdx.z;
  const u16* A = z ? A2 : A1;
  const u16* Bt = z ? M2 : M1;
  const float* sc = z ? s2 : s1;
  u16* O = z ? O2 : O1;
  int w = threadIdx.x >> 6, l = threadIdx.x & 63, r15 = l & 15, g = l >> 4;
  int i0 = blockIdx.y * 64 + w * 16;
  int n0 = blockIdx.x * 128;
  f32x4 zero = {0.f, 0.f, 0.f, 0.f};
  f32x4 acc[8];
  #pragma unroll
  for (int n = 0; n < 8; ++n) acc[n] = zero;
  const u16* arow = A + (size_t)(i0 + r15) * 256 + g * 8;
  #pragma unroll
  for (int kc = 0; kc < 8; ++kc) {
    bf16x8 a = *reinterpret_cast<const bf16x8*>(arow + kc * 32);
    #pragma unroll
    for (int n = 0; n < 8; ++n) {
      bf16x8 b = *reinterpret_cast<const bf16x8*>(Bt + (size_t)(n0 + n * 16 + r15) * 256 + kc * 32 + g * 8);
      acc[n] = mfma16(a, b, acc[n]);
    }
  }
  int io = i0 + g * 4;
  float s4[4];
  #pragma unroll
  for (int q = 0; q < 4; ++q) s4[q] = sc[io + q];
  #pragma unroll
  for (int n = 0; n < 8; ++n) {
    int c = n0 + n * 16 + r15;
    #pragma unroll
    for (int q = 0; q < 4; ++q)
      O[(size_t)(io + q) * 256 + c] = f2bf(acc[n][q] * s4[q]);
  }
}

// ======================= w2d =======================
__global__ void k_w2d(const u16* __restrict__ W2t, const float* __restrict__ ogs,
                      u16* __restrict__ W2d, float* __restrict__ yn) {
  __shared__ float red[256];
  int n = blockIdx.x, z = blockIdx.y, k = threadIdx.x;
  int map = (z == 0) ? 512 : (z == 1) ? 0 : (z == 2) ? 768 : 256;
  float y = ogs[map + k];
  float wv = bf2f(W2t[n * 256 + k]);
  W2d[z * 65536 + n * 256 + k] = f2bf(wv * y);
  red[k] = wv * y * y;
  __syncthreads();
  for (int s = 128; s > 0; s >>= 1) {
    if (k < s) red[k] += red[k + s];
    __syncthreads();
  }
  if (!k) yn[z * 256 + n] = rsqrtf(fmaxf(red[0], 1e-30f));
}

// ======================= match5: fused miu/phi/psi, LDS-staged A/Am (XOR-swizzled), 4 n-frags ======
// grid (4, 128, 2): 4 c-blocks of 64, 128 i-blocks of 64, 2 graphs. LDS 64KB -> 2 blk/CU.
__global__ __launch_bounds__(256, 2) void k_match5(
    const u16* __restrict__ h1b, const u16* __restrict__ h1mb,
    const u16* __restrict__ h2b, const u16* __restrict__ h2mb,
    const u16* __restrict__ W2t, const u16* __restrict__ W2dB, const float* __restrict__ ynB,
    u16* __restrict__ mb0, u16* __restrict__ mb1, u16* __restrict__ mb2,
    u16* __restrict__ mb3, u16* __restrict__ mb4, u16* __restrict__ mb5) {
  __shared__ __align__(16) u16 As[64 * 256];   // 32KB, [row][chunk^(row&7)]
  __shared__ __align__(16) u16 Ams[64 * 256];  // 32KB
  int z = blockIdx.z;
  const u16* A  = z ? h2b : h1b;
  const u16* Am = z ? h2mb : h1mb;
  const u16* Wphi = W2dB + (size_t)(z ? 2 : 0) * 65536;
  const u16* Wpsi = W2dB + (size_t)(z ? 3 : 1) * 65536;
  const float* ynphi = ynB + (z ? 512 : 0);
  const float* ynpsi = ynB + (z ? 768 : 256);
  u16* oMiu = z ? mb3 : mb0;
  u16* oPhi = z ? mb4 : mb1;
  u16* oPsi = z ? mb5 : mb2;
  int tid = threadIdx.x;
  int w = tid >> 6, l = tid & 63, r15 = l & 15, g = l >> 4;
  int i0 = blockIdx.y * 64;
  int n0 = blockIdx.x * 64;
  // stage both 32KB tiles; source chunk pre-swizzled so LDS[row][c] = G[row][c^(row&7)]
  {
    const u16* Ag = A + (size_t)i0 * 256;
    const u16* Mg = Am + (size_t)i0 * 256;
    #pragma unroll
    for (int p = 0; p < 8; ++p) {
      int cidx = p * 256 + tid;            // 16B-chunk slot, 0..2047
      int row = cidx >> 5, c = cidx & 31;
      int gs = (row << 5) + (c ^ (row & 7));
      gload16(Ag + gs * 8, As + cidx * 8);
      gload16(Mg + gs * 8, Ams + cidx * 8);
    }
  }
  __syncthreads();   // drains vmcnt: tiles resident
  f32x4 zero = {0.f, 0.f, 0.f, 0.f};
  f32x4 aP[4], aQ[4], aU[4], aD1[4], aD2[4];
  #pragma unroll
  for (int n = 0; n < 4; ++n) { aP[n] = zero; aQ[n] = zero; aU[n] = zero; aD1[n] = zero; aD2[n] = zero; }
  int arow = w * 16 + r15;                 // row in tile
  int rx = arow & 7;
  #pragma unroll
  for (int kc = 0; kc < 8; ++kc) {
    int lchunk = arow * 32 + (((kc << 2) + g) ^ rx);
    uint4 xa = *reinterpret_cast<const uint4*>(As + lchunk * 8);
    uint4 xc = *reinterpret_cast<const uint4*>(Ams + lchunk * 8);
    bf16x8 fa = *reinterpret_cast<const bf16x8*>(&xa);
    bf16x8 fc = *reinterpret_cast<const bf16x8*>(&xc);
    bf16x8 fu, fp, fq;
    float ta, tc;
    ta = bf2f((u16)(xa.x & 0xffff)); tc = bf2f((u16)(xc.x & 0xffff));
    fu[0] = (__bf16)(ta * tc); fp[0] = (__bf16)(ta * ta); fq[0] = (__bf16)(tc * tc);
    ta = bf2f((u16)(xa.x >> 16));    tc = bf2f((u16)(xc.x >> 16));
    fu[1] = (__bf16)(ta * tc); fp[1] = (__bf16)(ta * ta); fq[1] = (__bf16)(tc * tc);
    ta = bf2f((u16)(xa.y & 0xffff)); tc = bf2f((u16)(xc.y & 0xffff));
    fu[2] = (__bf16)(ta * tc); fp[2] = (__bf16)(ta * ta); fq[2] = (__bf16)(tc * tc);
    ta = bf2f((u16)(xa.y >> 16));    tc = bf2f((u16)(xc.y >> 16));
    fu[3] = (__bf16)(ta * tc); fp[3] = (__bf16)(ta * ta); fq[3] = (__bf16)(tc * tc);
    ta = bf2f((u16)(xa.z & 0xffff)); tc = bf2f((u16)(xc.z & 0xffff));
    fu[4] = (__bf16)(ta * tc); fp[4] = (__bf16)(ta * ta); fq[4] = (__bf16)(tc * tc);
    ta = bf2f((u16)(xa.z >> 16));    tc = bf2f((u16)(xc.z >> 16));
    fu[5] = (__bf16)(ta * tc); fp[5] = (__bf16)(ta * ta); fq[5] = (__bf16)(tc * tc);
    ta = bf2f((u16)(xa.w & 0xffff)); tc = bf2f((u16)(xc.w & 0xffff));
    fu[6] = (__bf16)(ta * tc); fp[6] = (__bf16)(ta * ta); fq[6] = (__bf16)(tc * tc);
    ta = bf2f((u16)(xa.w >> 16));    tc = bf2f((u16)(xc.w >> 16));
    fu[7] = (__bf16)(ta * tc); fp[7] = (__bf16)(ta * ta); fq[7] = (__bf16)(tc * tc);
    #pragma unroll
    for (int n = 0; n < 4; ++n) {
      size_t boff = (size_t)(n0 + n * 16 + r15) * 256 + kc * 32 + g * 8;
      bf16x8 bw = *reinterpret_cast<const bf16x8*>(W2t + boff);
      aP[n] = mfma16(fp, bw, aP[n]);
      aQ[n] = mfma16(fq, bw, aQ[n]);
      aU[n] = mfma16(fu, bw, aU[n]);
      bf16x8 b1 = *reinterpret_cast<const bf16x8*>(Wphi + boff);
      aD1[n] = mfma16(fa, b1, aD1[n]);
      bf16x8 b2 = *reinterpret_cast<const bf16x8*>(Wpsi + boff);
      aD2[n] = mfma16(fc, b2, aD2[n]);
    }
  }
  int io = i0 + w * 16 + g * 4;
  #pragma unroll
  for (int n = 0; n < 4; ++n) {
    int c = n0 + n * 16 + r15;
    float y1 = ynphi[c], y2 = ynpsi[c];
    #pragma unroll
    for (int q = 0; q < 4; ++q) {
      float rp = rsqrtf(fmaxf(aP[n][q], 1e-30f));
      float rq = rsqrtf(fmaxf(aQ[n][q], 1e-30f));
      size_t idx = (size_t)(io + q) * 256 + c;
      oMiu[idx] = f2bf(aU[n][q] * rp * rq);
      oPhi[idx] = f2bf(aD1[n][q] * rp * y1);
      oPsi[idx] = f2bf(aD2[n][q] * rq * y2);
    }
  }
}

// ======================= scalar match pair (om1/om2: 1x256 each) =======================
__global__ void k_match_g(const float* __restrict__ X1, const float* __restrict__ Y1,
                          const float* __restrict__ X2, const float* __restrict__ Y2,
                          const float* __restrict__ W2, float* __restrict__ v) {
  __shared__ float u[256], p[256], q[256];
  const float* X = blockIdx.x ? X2 : X1;
  const float* Y = blockIdx.x ? Y2 : Y1;
  float* o = v + (blockIdx.x ? 1792 : 768);
  int t = threadIdx.x;
  float xv = X[t], yv = Y[t];
  u[t] = xv * yv; p[t] = xv * xv; q[t] = yv * yv;
  __syncthreads();
  float a = 0.f, b = 0.f, c = 0.f;
  #pragma unroll 4
  for (int d = 0; d < 256; ++d) {
    float wv = W2[(size_t)d * DDIM + t];
    a += u[d] * wv; b += p[d] * wv; c += q[d] * wv;
  }
  o[t] = a / fmaxf(sqrtf(b) * sqrtf(c), FEPS);
}

__global__ void k_w2(const float* __restrict__ Wm, float* __restrict__ W2, int n) {
  int i = blockIdx.x * blockDim.x + threadIdx.x;
  if (i < n) { float v = Wm[i]; W2[i] = v * v; }
}

// ======================= batched readouts (bf16 inputs) =======================
__global__ void k_bmu_b(PLB L, float* __restrict__ mu) {
  const u16* h = L.p[blockIdx.y];
  int d = threadIdx.x;
  int r0 = blockIdx.x * 128;
  float acc = 0.f;
  for (int r = 0; r < 128; ++r) acc += bf2f(h[(size_t)(r0 + r) * 256 + d]);
  atomicAdd(&mu[blockIdx.y * 256 + d], acc);
}

__global__ void k_bgv(const float* __restrict__ mu, const float* __restrict__ Wr,
                      float* __restrict__ g) {
  __shared__ float ls[256];
  int m = blockIdx.x, t = threadIdx.x;
  ls[t] = mu[m * 256 + t] * (1.f / (float)NN);
  __syncthreads();
  float acc = 0.f;
  #pragma unroll 4
  for (int d = 0; d < 256; ++d) acc += ls[d] * Wr[(size_t)d * 256 + t];
  g[m * 256 + t] = tanhf(acc);
}

__global__ __launch_bounds__(256) void k_bsc_b(PLB L, const float* __restrict__ g,
                                               float* __restrict__ v) {
  __shared__ __align__(16) float gs[256];
  __shared__ float sarr[32];
  int m = blockIdx.y;
  const u16* h = L.p[m];
  int t = threadIdx.x, w = t >> 6, l = t & 63;
  gs[t] = g[m * 256 + t];
  __syncthreads();
  int r0 = blockIdx.x * 32;
  float4 gv4 = reinterpret_cast<const float4*>(gs)[l];
  for (int rr = w * 8; rr < w * 8 + 8; ++rr) {
    ushort4 hv = *reinterpret_cast<const ushort4*>(h + (size_t)(r0 + rr) * 256 + l * 4);
    float dot = bf2f(hv.x) * gv4.x + bf2f(hv.y) * gv4.y + bf2f(hv.z) * gv4.z + bf2f(hv.w) * gv4.w;
    #pragma unroll
    for (int o = 32; o > 0; o >>= 1) dot += __shfl_xor(dot, o);
    if (!l) sarr[rr] = 1.f / (1.f + expf(-dot));
  }
  __syncthreads();
  float acc = 0.f;
  for (int rr = 0; rr < 32; ++rr) acc += sarr[rr] * bf2f(h[(size_t)(r0 + rr) * 256 + t]);
  atomicAdd(&v[L.slot[m] + t], acc);
}

// ======================= MLP (split-K parallel GEMV) =======================
__global__ void k_binit(const float* __restrict__ b1, const float* __restrict__ b2,
                        const float* __restrict__ b3, float* __restrict__ l1,
                        float* __restrict__ l2, float* __restrict__ l3) {
  int t = blockIdx.x * 256 + threadIdx.x;
  if (t < 512) l1[t] = b1[t];
  if (t < 256) l2[t] = b2[t];
  if (t < 128) l3[t] = b3[t];
}

__global__ void k_gemv(const float* __restrict__ vin, const float* __restrict__ w,
                       float* __restrict__ out, int K, int M, int Kc, int relu_in) {
  int m = blockIdx.x * 256 + threadIdx.x;
  if (m >= M) return;
  int k0 = blockIdx.y * Kc;
  float acc = 0.f;
  #pragma unroll 4
  for (int k = k0; k < k0 + Kc; ++k) {
    float x = vin[k];
    if (relu_in) x = fmaxf(x, 0.f);
    acc += x * w[(size_t)k * M + m];
  }
  atomicAdd(&out[m], acc);
}

__global__ void k_final(const float* __restrict__ l3, const float* __restrict__ w4,
                        const float* __restrict__ b4, const int* __restrict__ label,
                        float* __restrict__ out) {
  __shared__ float ls[128];
  int t = threadIdx.x;
  ls[t] = fmaxf(l3[t], 0.f) * w4[t];
  __syncthreads();
  for (int w = 64; w > 0; w >>= 1) { if (t < w) ls[t] += ls[t + w]; __syncthreads(); }
  if (t == 0) {
    float z = 1.f / (1.f + expf(-(ls[0] + b4[0])));
    out[0] = z;
    float lb = (float)label[0];
    out[1] = lb;
    out[2] = expf(-lb);
  }
}

// ======================= host =======================
extern "C" void kernel_launch(void* const* d_in, const int* in_sizes, int n_in,
                              void* d_out, int out_size, void* d_ws, size_t ws_size,
                              hipStream_t stream) {
  (void)in_sizes; (void)n_in; (void)out_size;
  const float* x_s   = (const float*)d_in[0];
  const float* x_t   = (const float*)d_in[1];
  const int*   ei_s  = (const int*)d_in[2];
  const int*   ei_t  = (const int*)d_in[3];
  const int*   label = (const int*)d_in[4];
  const float* W_g1  = (const float*)d_in[5];
  const float* a1s   = (const float*)d_in[6];
  const float* a1d   = (const float*)d_in[7];
  const float* W_g2  = (const float*)d_in[8];
  const float* a2s   = (const float*)d_in[9];
  const float* a2d   = (const float*)d_in[10];
  const float* W_read  = (const float*)d_in[11];
  const float* W_match = (const float*)d_in[12];
  const float* w1 = (const float*)d_in[13]; const float* b1 = (const float*)d_in[14];
  const float* w2 = (const float*)d_in[15]; const float* b2 = (const float*)d_in[16];
  const float* w3 = (const float*)d_in[17]; const float* b3 = (const float*)d_in[18];
  const float* w4 = (const float*)d_in[19]; const float* b4 = (const float*)d_in[20];
  float* out = (float*)d_out;

  char* base = (char*)d_ws;
  size_t off = 0;
  auto alloc = [&](size_t bytes) -> void* {
    void* pp = base + off;
    off = (off + bytes + 255) & ~(size_t)255;
    return pp;
  };
  double* dsum = (double*)alloc(4 * sizeof(double));
  u16*   gb   = (u16*)alloc((size_t)NN * HH * 2);
  u16*   h2pb = (u16*)alloc((size_t)NN * DDIM * 2);
  u16*   aggfb= (u16*)alloc((size_t)NN * FF * 2);
  float* h1   = (float*)alloc((size_t)NN * DDIM * 4);
  float* h2   = (float*)alloc((size_t)NN * DDIM * 4);
  u16*   f1b  = (u16*)alloc((size_t)NN * FF * 2);
  u16*   f2b  = (u16*)alloc((size_t)NN * FF * 2);
  u16*   h1b  = (u16*)alloc((size_t)NN * DDIM * 2);
  u16*   h2b  = (u16*)alloc((size_t)NN * DDIM * 2);
  u16*   h1mb = (u16*)alloc((size_t)NN * DDIM * 2);
  u16*   h2mb = (u16*)alloc((size_t)NN * DDIM * 2);
  u16*   h1t  = (u16*)alloc((size_t)NN * DDIM * 2);
  u16*   h2t  = (u16*)alloc((size_t)NN * DDIM * 2);
  u16*   wh1t = (u16*)alloc((size_t)NN * DDIM * 2);
  u16*   wh2t = (u16*)alloc((size_t)NN * DDIM * 2);
  u16*   mb0  = (u16*)alloc((size_t)NN * DDIM * 2);
  u16*   mb1  = (u16*)alloc((size_t)NN * DDIM * 2);
  u16*   mb2  = (u16*)alloc((size_t)NN * DDIM * 2);
  u16*   mb3  = (u16*)alloc((size_t)NN * DDIM * 2);
  u16*   mb4  = (u16*)alloc((size_t)NN * DDIM * 2);
  u16*   mb5  = (u16*)alloc((size_t)NN * DDIM * 2);
  float* alpha= (float*)alloc((size_t)ET * 4);
  int*   srcs = (int*)alloc((size_t)ET * 4);
  int*   deg  = (int*)alloc(NN * 4);
  int*   curs = (int*)alloc(NN * 4);
  int*   offs = (int*)alloc((NN + 1) * 4);
  float* n1inv= (float*)alloc(NN * 4);
  float* n2inv= (float*)alloc(NN * 4);
  float* Rr   = (float*)alloc(NN * 4);
  float* Ss   = (float*)alloc(NN * 4);
  float* scj1 = (float*)alloc(NN * 4);
  float* scj2 = (float*)alloc(NN * 4);
  float* hsb  = (float*)alloc(NN * 4);
  float* hdb  = (float*)alloc(NN * 4);
  float* W2   = (float*)alloc((size_t)DDIM * DDIM * 4);
  u16*   Wg1t = (u16*)alloc((size_t)HH * FF * 2);
  u16*   Wg2t = (u16*)alloc((size_t)DDIM * HH * 2);
  u16*   W2t  = (u16*)alloc((size_t)DDIM * DDIM * 2);
  u16*   W2dB = (u16*)alloc(4 * 65536 * 2);
  float* ynB  = (float*)alloc(4 * 256 * 4);
  u16*   Mb   = (u16*)alloc(2 * 65536 * 2);
  float* wa   = (float*)alloc(1280 * 4);
  float* mug1 = (float*)alloc(4 * 256 * 4);
  float* ogs  = (float*)alloc(4 * 256 * 4);
  float* mug2 = (float*)alloc(6 * 256 * 4);
  float* v    = (float*)alloc(2048 * 4);
  float* ut   = (float*)alloc(512 * 4);
  float* Mf   = (float*)alloc(2 * 65536 * 4);
  float* g1   = (float*)alloc(4 * 256 * 4);
  float* g2   = (float*)alloc(6 * 256 * 4);
  float* l1o  = (float*)alloc(512 * 4);
  float* l2o  = (float*)alloc(256 * 4);
  float* l3o  = (float*)alloc(128 * 4);
  if (off > ws_size) return;

  float* h1g  = ogs + 0;
  float* h2g  = ogs + 256;
  float* h1mg = ogs + 512;
  float* h2mg = ogs + 768;
  const size_t zr_bytes = (4 * 256 + 4 * 256 + 6 * 256 + 2048 + 512 + 2 * 65536) * 4;

  // ---- stage 0 ----
  hipMemsetAsync(dsum, 0, 4 * sizeof(double), stream);
  k_reduce2<<<dim3(1024, 2), 256, 0, stream>>>(x_s, x_t, NN * FF, dsum);
  k_normalize2<<<dim3(1024, 2), 256, 0, stream>>>(x_s, x_t, f1b, f2b, NN * FF, dsum);

  // ---- weight preps ----
  k_tr_bf16<<<dim3(HH / 32, FF / 32), 256, 0, stream>>>(W_g1, Wg1t, FF, HH, 0);
  k_tr_bf16<<<dim3(DDIM / 32, HH / 32), 256, 0, stream>>>(W_g2, Wg2t, HH, DDIM, 0);
  k_tr_bf16<<<dim3(DDIM / 32, DDIM / 32), 256, 0, stream>>>(W_match, W2t, DDIM, DDIM, 1);
  k_w2<<<dim3((DDIM * DDIM + 255) / 256), 256, 0, stream>>>(W_match, W2, DDIM * DDIM);
  k_wa<<<dim3(2), 256, 0, stream>>>(W_g1, a1s, a1d, W_g2, a2s, a2d, wa);

  // ---- GAT ----
  auto run_gat = [&](const u16* finb, const int* ei, float* hout, u16* houtb) {
    hipMemsetAsync(deg, 0, NN * 4, stream);
    k_hist<<<dim3((ET + 255) / 256), 256, 0, stream>>>(ei, deg);
    k_scan<<<1, 256, 0, stream>>>(deg, offs, curs);
    k_scatter<<<dim3((ET + 255) / 256), 256, 0, stream>>>(ei, curs, srcs);
    k_dots1<<<dim3(NN / 4), 256, 0, stream>>>(finb, wa, hsb, hdb);
    k_alpha<<<dim3(NN / 4), 256, 0, stream>>>(offs, srcs, hsb, hdb, alpha);
    k_aggf<<<dim3(NN / 4), 256, 0, stream>>>(offs, srcs, alpha, finb, aggfb);
    hipMemsetAsync(hsb, 0, 2 * NN * 4, stream);
    k_gemm_bf<<<dim3(HH / 128, NN / 64), 256, 0, stream>>>(aggfb, Wg1t, gb, FF, HH, 1,
                                                           wa + 256, wa + 768, hsb, hdb);
    k_alpha<<<dim3(NN / 4), 256, 0, stream>>>(offs, srcs, hsb, hdb, alpha);
    k_gemm_bf<<<dim3(DDIM / 128, NN / 64), 256, 0, stream>>>(gb, Wg2t, h2pb, HH, DDIM, 0,
                                                             nullptr, nullptr, nullptr, nullptr);
    k_agg3<<<dim3(NN / 4), 256, 0, stream>>>(offs, srcs, alpha, h2pb, hout, houtb);
  };
  run_gat(f1b, ei_s, h1, h1b);
  run_gat(f2b, ei_t, h2, h2b);

  // ---- mutual (rank-256 collapse) ----
  k_rninv2<<<dim3(NN / 4, 2), 256, 0, stream>>>(h1, h2, n1inv, n2inv);
  hipMemsetAsync(mug1, 0, zr_bytes, stream);
  k_wsum<<<dim3(64, 2), 256, 0, stream>>>(h1, h2, n1inv, n2inv, ut);
  k_rs<<<dim3(NN / 4, 2), 256, 0, stream>>>(h1, h2, n1inv, n2inv, ut, Rr, Ss);
  k_scj<<<dim3(NN / 256), 256, 0, stream>>>(Ss, Rr, n1inv, n2inv, scj1, scj2);
  k_tr2w<<<dim3(DDIM / 32, NN / 32, 2), 256, 0, stream>>>(h2, scj1, h2t, wh2t, h1, scj2, h1t, wh1t);
  k_gemm_M<<<dim3(2, 4, 32), 256, 0, stream>>>(wh2t, h2t, wh1t, h1t, Mf);
  k_m2bf<<<dim3(256, 2), 256, 0, stream>>>(Mf, Mb);
  k_gemm_hm<<<dim3(2, 128, 2), 256, 0, stream>>>(h1b, Mb, n1inv, h1mb,
                                                 h2b, Mb + 65536, n2inv, h2mb);

  // ---- readout group 1: h1, h2, h1m, h2m (bf16) ----
  PLB g1l;
  g1l.p[0] = h1b;  g1l.slot[0] = 0;
  g1l.p[1] = h2b;  g1l.slot[1] = 256;
  g1l.p[2] = h1mb; g1l.slot[2] = 512;
  g1l.p[3] = h2mb; g1l.slot[3] = 768;
  k_bmu_b<<<dim3(64, 4), 256, 0, stream>>>(g1l, mug1);
  k_bgv<<<dim3(4), 256, 0, stream>>>(mug1, W_read, g1);
  k_bsc_b<<<dim3(256, 4), 256, 0, stream>>>(g1l, g1, ogs);

  // ---- matches (fused 5-chain kernel, LDS-staged, swizzled) ----
  k_w2d<<<dim3(256, 4), 256, 0, stream>>>(W2t, ogs, W2dB, ynB);
  k_match5<<<dim3(4, 128, 2), 256, 0, stream>>>(h1b, h1mb, h2b, h2mb, W2t, W2dB, ynB,
                                                mb0, mb1, mb2, mb3, mb4, mb5);
  k_match_g<<<dim3(2), 256, 0, stream>>>(h1g, h1mg, h2g, h2mg, W2, v);

  // ---- readout group 2: 6 bf16 match outputs -> v slots ----
  PLB g2l;
  g2l.p[0] = mb0; g2l.slot[0] = 0;
  g2l.p[1] = mb1; g2l.slot[1] = 256;
  g2l.p[2] = mb2; g2l.slot[2] = 512;
  g2l.p[3] = mb3; g2l.slot[3] = 1024;
  g2l.p[4] = mb4; g2l.slot[4] = 1280;
  g2l.p[5] = mb5; g2l.slot[5] = 1536;
  k_bmu_b<<<dim3(64, 6), 256, 0, stream>>>(g2l, mug2);
  k_bgv<<<dim3(6), 256, 0, stream>>>(mug2, W_read, g2);
  k_bsc_b<<<dim3(256, 6), 256, 0, stream>>>(g2l, g2, v);

  // ---- MLP (split-K gemv) ----
  k_binit<<<dim3(2), 256, 0, stream>>>(b1, b2, b3, l1o, l2o, l3o);
  k_gemv<<<dim3(2, 16), 256, 0, stream>>>(v, w1, l1o, 2048, 512, 128, 0);
  k_gemv<<<dim3(1, 8), 256, 0, stream>>>(l1o, w2, l2o, 512, 256, 64, 1);
  k_gemv<<<dim3(1, 8), 256, 0, stream>>>(l2o, w3, l3o, 256, 128, 32, 1);
  k_final<<<1, 128, 0, stream>>>(l3o, w4, b4, label, out);
}